// Round 4
// baseline (10554.515 us; speedup 1.0000x reference)
//
#include <hip/hip_runtime.h>
#include <hip/hip_bf16.h>

#define N_NODES 100000
#define NPAD    100096   // 782 * 128
#define N_EDGES 1600000
#define HDIM 128
#define NLAYERS 4
#define NGRAPH 256
#define ENCDIM 256
#define EPS_BN 1e-5f

typedef __attribute__((ext_vector_type(8))) short bf16x8;
typedef __attribute__((ext_vector_type(4))) float f32x4;

__device__ __forceinline__ unsigned short f2bf(float v) {
    unsigned int u = __float_as_uint(v);
    u += 0x7FFFu + ((u >> 16) & 1u);
    return (unsigned short)(u >> 16);
}
__device__ __forceinline__ float bf2f(unsigned int lo16) {
    return __uint_as_float(lo16 << 16);
}

// frag-order index (in ushorts) for element (row n, feature f) of a [NPAD x 128] matrix:
// t=n>>4, r16=n&15, ks=f>>5, kq=(f>>3)&3, j=f&7
// idx = (((t*4 + ks)*64) + kq*16 + r16)*8 + j
// A wave's MFMA A-load for (tile t, ks) is then 64 lanes x 8 ushorts contiguous.

// ---------------- CSR build ----------------
__global__ void k_count(const int* __restrict__ dst, int* __restrict__ cnt) {
    int e = blockIdx.x * 256 + threadIdx.x;
    if (e < N_EDGES) atomicAdd(&cnt[dst[e]], 1);
}

__global__ void k_dinv(const int* __restrict__ cnt, float* __restrict__ dinv) {
    int n = blockIdx.x * 256 + threadIdx.x;
    if (n < N_NODES) dinv[n] = rsqrtf((float)cnt[n] + 1.0f);
}

__global__ void k_scan_block(const int* __restrict__ cnt, int* __restrict__ excl,
                             int* __restrict__ bsums) {
    __shared__ int s[256];
    int t = threadIdx.x;
    int i = blockIdx.x * 256 + t;
    int v = (i < N_NODES) ? cnt[i] : 0;
    s[t] = v;
    __syncthreads();
    for (int off = 1; off < 256; off <<= 1) {
        int x = 0;
        if (t >= off) x = s[t - off];
        __syncthreads();
        if (t >= off) s[t] += x;
        __syncthreads();
    }
    if (i < N_NODES) excl[i] = s[t] - v;
    if (t == 255) bsums[blockIdx.x] = s[255];
}

__global__ void k_scan_sums(int* __restrict__ bsums, int nb) {
    __shared__ int s[512];
    int t = threadIdx.x;
    int v = (t < nb) ? bsums[t] : 0;
    s[t] = v;
    __syncthreads();
    for (int off = 1; off < 512; off <<= 1) {
        int x = 0;
        if (t >= off) x = s[t - off];
        __syncthreads();
        if (t >= off) s[t] += x;
        __syncthreads();
    }
    if (t < nb) bsums[t] = s[t] - v;
}

__global__ void k_scan_add(int* __restrict__ excl, const int* __restrict__ bsums,
                           int* __restrict__ cursor) {
    int i = blockIdx.x * 256 + threadIdx.x;
    if (i < N_NODES) {
        int v = excl[i] + bsums[blockIdx.x];
        excl[i] = v;
        cursor[i] = v;
    }
}

__global__ void k_scatter(const int* __restrict__ src, const int* __restrict__ dst,
                          const float* __restrict__ dinv, int* __restrict__ cursor,
                          int2* __restrict__ csr_ew) {
    int e = blockIdx.x * 256 + threadIdx.x;
    if (e < N_EDGES) {
        int d = dst[e];
        int s = src[e];
        int p = atomicAdd(&cursor[d], 1);
        int2 v;
        v.x = s;
        v.y = __float_as_int(dinv[s] * dinv[d]);
        csr_ew[p] = v;
    }
}

// ---------------- graph bounds via binary search (batch is sorted) ----------------
__global__ void k_gbounds(const int* __restrict__ batch, int* __restrict__ gstart,
                          int* __restrict__ gcnt) {
    __shared__ int s[257];
    int g = threadIdx.x;  // 256 threads
    int lo = 0, hi = N_NODES;
    while (lo < hi) {
        int mid = (lo + hi) >> 1;
        if (batch[mid] < g) lo = mid + 1; else hi = mid;
    }
    s[g] = lo;
    if (g == 255) s[256] = N_NODES;
    __syncthreads();
    gstart[g] = s[g];
    gcnt[g] = s[g + 1] - s[g];
}

// ---------------- weight -> MFMA B-fragment order, split hi/lo ----------------
__global__ void k_wfrag(const float* __restrict__ W, int ldw, int ntiles,
                        unsigned short* __restrict__ Fh, unsigned short* __restrict__ Fl) {
    int t = blockIdx.x * 256 + threadIdx.x;
    if (t >= ntiles * 256) return;
    int lane = t & 63, ks = (t >> 6) & 3, nt = t >> 8;
    int r16 = lane & 15, kq = lane >> 4;
    unsigned short h[8], l[8];
#pragma unroll
    for (int j = 0; j < 8; j++) {
        float w = W[(size_t)(ks * 32 + kq * 8 + j) * ldw + nt * 16 + r16];
        unsigned short hh = f2bf(w);
        h[j] = hh;
        l[j] = f2bf(w - bf2f(hh));
    }
    ((ushort4*)(Fh + (size_t)t * 8))[0] = make_ushort4(h[0], h[1], h[2], h[3]);
    ((ushort4*)(Fh + (size_t)t * 8))[1] = make_ushort4(h[4], h[5], h[6], h[7]);
    ((ushort4*)(Fl + (size_t)t * 8))[0] = make_ushort4(l[0], l[1], l[2], l[3]);
    ((ushort4*)(Fl + (size_t)t * 8))[1] = make_ushort4(l[4], l[5], l[6], l[7]);
}

// ---------------- x -> hi/lo bf16, frag-ordered (pads zeroed) ----------------
__global__ __launch_bounds__(256) void k_split_x(const float4* __restrict__ x4,
                                                 unsigned short* __restrict__ Uh,
                                                 unsigned short* __restrict__ Ul) {
    size_t i = (size_t)blockIdx.x * 256 + threadIdx.x;  // NPAD*32 float4s
    size_t n = i >> 5;
    int fl = (int)(i & 31);
    float4 v = make_float4(0.f, 0.f, 0.f, 0.f);
    if (n < N_NODES) v = x4[i];
    ushort4 h, l;
    h.x = f2bf(v.x); l.x = f2bf(v.x - bf2f(h.x));
    h.y = f2bf(v.y); l.y = f2bf(v.y - bf2f(h.y));
    h.z = f2bf(v.z); l.z = f2bf(v.z - bf2f(h.z));
    h.w = f2bf(v.w); l.w = f2bf(v.w - bf2f(h.w));
    size_t idx = ((((n >> 4) * 4 + (fl >> 3)) * 64) + ((fl >> 1) & 3) * 16 + (n & 15)) * 8
                 + (fl & 1) * 4;
    *(ushort4*)(Uh + idx) = h;
    *(ushort4*)(Ul + idx) = l;
}

// ---------------- split-bf16 MFMA GEMM (frag-ordered A) ----------------
template <int ACC>
__global__ __launch_bounds__(256) void k_mfma(const unsigned short* __restrict__ Ah,
                                              const unsigned short* __restrict__ Al,
                                              const unsigned short* __restrict__ Fh,
                                              const unsigned short* __restrict__ Fl,
                                              float* __restrict__ C, int ldc) {
    int lane = threadIdx.x & 63;
    int wid = threadIdx.x >> 6;
    int r16 = lane & 15, kq = lane >> 4;
    size_t mrow0 = (size_t)blockIdx.x * 128 + wid * 32;
    int colOff = blockIdx.y * 128;
    int ntBase = blockIdx.y * 8;

    bf16x8 ah[2][4], al[2][4];
#pragma unroll
    for (int mt = 0; mt < 2; mt++) {
        size_t tt = (size_t)blockIdx.x * 8 + wid * 2 + mt;
#pragma unroll
        for (int ks = 0; ks < 4; ks++) {
            size_t idx = ((tt * 4 + ks) * 64 + lane) * 8;
            ah[mt][ks] = *reinterpret_cast<const bf16x8*>(Ah + idx);
            al[mt][ks] = *reinterpret_cast<const bf16x8*>(Al + idx);
        }
    }

    f32x4 acc[2][8];
#pragma unroll
    for (int mt = 0; mt < 2; mt++)
#pragma unroll
        for (int nt = 0; nt < 8; nt++) acc[mt][nt] = (f32x4){0.f, 0.f, 0.f, 0.f};

#pragma unroll
    for (int nt = 0; nt < 8; nt++) {
        const unsigned short* pbh = Fh + ((size_t)(ntBase + nt) * 4 * 64 + lane) * 8;
        const unsigned short* pbl = Fl + ((size_t)(ntBase + nt) * 4 * 64 + lane) * 8;
        bf16x8 bh[4], bl[4];
#pragma unroll
        for (int ks = 0; ks < 4; ks++) {
            bh[ks] = *reinterpret_cast<const bf16x8*>(pbh + ks * 512);
            bl[ks] = *reinterpret_cast<const bf16x8*>(pbl + ks * 512);
        }
#pragma unroll
        for (int mt = 0; mt < 2; mt++)
#pragma unroll
            for (int ks = 0; ks < 4; ks++) {
                acc[mt][nt] = __builtin_amdgcn_mfma_f32_16x16x32_bf16(ah[mt][ks], bl[ks],
                                                                     acc[mt][nt], 0, 0, 0);
                acc[mt][nt] = __builtin_amdgcn_mfma_f32_16x16x32_bf16(al[mt][ks], bh[ks],
                                                                     acc[mt][nt], 0, 0, 0);
                acc[mt][nt] = __builtin_amdgcn_mfma_f32_16x16x32_bf16(ah[mt][ks], bh[ks],
                                                                     acc[mt][nt], 0, 0, 0);
            }
    }

#pragma unroll
    for (int mt = 0; mt < 2; mt++)
#pragma unroll
        for (int nt = 0; nt < 8; nt++)
#pragma unroll
            for (int r = 0; r < 4; r++) {
                size_t row = mrow0 + mt * 16 + kq * 4 + r;
                float* cp = C + row * ldc + colOff + nt * 16 + r16;
                float v = acc[mt][nt][r];
                if (ACC) v += *cp;
                *cp = v;
            }
}

// ---------------- aggregation + fused BN stats ----------------
// One wave per node: halves process even/odd edges (unroll 4 each -> 8 gathers
// in flight per node); combine via shfl_xor(32). Output written frag-ordered.
__global__ __launch_bounds__(256) void k_agg(const float4* __restrict__ hw4,
                                             const int* __restrict__ rs,
                                             const int* __restrict__ cnt,
                                             const int2* __restrict__ csr_ew,
                                             const float* __restrict__ dinv,
                                             const float4* __restrict__ bias4,
                                             unsigned short* __restrict__ Uh,
                                             unsigned short* __restrict__ Ul,
                                             float* __restrict__ bnsum,
                                             float* __restrict__ bnsq) {
    int n = blockIdx.x * 4 + (threadIdx.x >> 6);
    int lane = threadIdx.x & 63;
    int fl = lane & 31;
    int half = lane >> 5;
    float d = dinv[n];
    float dd = d * d;
    float4 acc = make_float4(0.f, 0.f, 0.f, 0.f);
    if (half == 0) {
        float4 self = hw4[(size_t)n * 32 + fl];
        float4 b = bias4[fl];
        acc.x = fmaf(dd, self.x, b.x);
        acc.y = fmaf(dd, self.y, b.y);
        acc.z = fmaf(dd, self.z, b.z);
        acc.w = fmaf(dd, self.w, b.w);
    }
    int s0 = rs[n];
    int c = cnt[n];
    int e = half;
    for (; e + 6 < c; e += 8) {
        int2 e0 = csr_ew[s0 + e];
        int2 e1 = csr_ew[s0 + e + 2];
        int2 e2 = csr_ew[s0 + e + 4];
        int2 e3 = csr_ew[s0 + e + 6];
        float4 v0 = hw4[(size_t)e0.x * 32 + fl];
        float4 v1 = hw4[(size_t)e1.x * 32 + fl];
        float4 v2 = hw4[(size_t)e2.x * 32 + fl];
        float4 v3 = hw4[(size_t)e3.x * 32 + fl];
        float w0 = __int_as_float(e0.y);
        float w1 = __int_as_float(e1.y);
        float w2 = __int_as_float(e2.y);
        float w3 = __int_as_float(e3.y);
        acc.x = fmaf(w0, v0.x, acc.x); acc.y = fmaf(w0, v0.y, acc.y);
        acc.z = fmaf(w0, v0.z, acc.z); acc.w = fmaf(w0, v0.w, acc.w);
        acc.x = fmaf(w1, v1.x, acc.x); acc.y = fmaf(w1, v1.y, acc.y);
        acc.z = fmaf(w1, v1.z, acc.z); acc.w = fmaf(w1, v1.w, acc.w);
        acc.x = fmaf(w2, v2.x, acc.x); acc.y = fmaf(w2, v2.y, acc.y);
        acc.z = fmaf(w2, v2.z, acc.z); acc.w = fmaf(w2, v2.w, acc.w);
        acc.x = fmaf(w3, v3.x, acc.x); acc.y = fmaf(w3, v3.y, acc.y);
        acc.z = fmaf(w3, v3.z, acc.z); acc.w = fmaf(w3, v3.w, acc.w);
    }
    for (; e < c; e += 2) {
        int2 ee = csr_ew[s0 + e];
        float4 v = hw4[(size_t)ee.x * 32 + fl];
        float w = __int_as_float(ee.y);
        acc.x = fmaf(w, v.x, acc.x); acc.y = fmaf(w, v.y, acc.y);
        acc.z = fmaf(w, v.z, acc.z); acc.w = fmaf(w, v.w, acc.w);
    }
    // combine halves
    acc.x += __shfl_xor(acc.x, 32);
    acc.y += __shfl_xor(acc.y, 32);
    acc.z += __shfl_xor(acc.z, 32);
    acc.w += __shfl_xor(acc.w, 32);

    __shared__ float4 ssum[128], ssq[128];
    if (half == 0) {
        // frag-ordered hi/lo write
        ushort4 hv, lv;
        hv.x = f2bf(acc.x); lv.x = f2bf(acc.x - bf2f(hv.x));
        hv.y = f2bf(acc.y); lv.y = f2bf(acc.y - bf2f(hv.y));
        hv.z = f2bf(acc.z); lv.z = f2bf(acc.z - bf2f(hv.z));
        hv.w = f2bf(acc.w); lv.w = f2bf(acc.w - bf2f(hv.w));
        size_t idx = ((((size_t)(n >> 4) * 4 + (fl >> 3)) * 64) + ((fl >> 1) & 3) * 16
                      + (n & 15)) * 8 + (fl & 1) * 4;
        *(ushort4*)(Uh + idx) = hv;
        *(ushort4*)(Ul + idx) = lv;
        int y = threadIdx.x >> 6;
        ssum[y * 32 + fl] = acc;
        float4 q;
        q.x = acc.x * acc.x; q.y = acc.y * acc.y;
        q.z = acc.z * acc.z; q.w = acc.w * acc.w;
        ssq[y * 32 + fl] = q;
    }
    __syncthreads();
    if (threadIdx.x < 32) {
        int t = threadIdx.x;
        float4 s = ssum[t], q = ssq[t];
#pragma unroll
        for (int y = 1; y < 4; y++) {
            float4 a = ssum[y * 32 + t], b = ssq[y * 32 + t];
            s.x += a.x; s.y += a.y; s.z += a.z; s.w += a.w;
            q.x += b.x; q.y += b.y; q.z += b.z; q.w += b.w;
        }
        atomicAdd(&bnsum[t * 4 + 0], s.x);
        atomicAdd(&bnsum[t * 4 + 1], s.y);
        atomicAdd(&bnsum[t * 4 + 2], s.z);
        atomicAdd(&bnsum[t * 4 + 3], s.w);
        atomicAdd(&bnsq[t * 4 + 0], q.x);
        atomicAdd(&bnsq[t * 4 + 1], q.y);
        atomicAdd(&bnsq[t * 4 + 2], q.z);
        atomicAdd(&bnsq[t * 4 + 3], q.w);
    }
}

// ---------------- BN finalize + apply (frag-ordered elementwise) ----------------
__global__ void k_bn_finalize(const float* __restrict__ sum, const float* __restrict__ sq,
                              const float* __restrict__ gamma, const float* __restrict__ beta,
                              float* __restrict__ scale, float* __restrict__ shift) {
    int f = threadIdx.x;
    float mu = sum[f] * (1.0f / N_NODES);
    float var = sq[f] * (1.0f / N_NODES) - mu * mu;
    float s = rsqrtf(var + EPS_BN) * gamma[f];
    scale[f] = s;
    shift[f] = beta[f] - mu * s;
}

__global__ __launch_bounds__(256) void k_bn_apply(unsigned int* __restrict__ H,
                                                  unsigned int* __restrict__ L,
                                                  const float* __restrict__ scale,
                                                  const float* __restrict__ shift) {
    size_t i = (size_t)blockIdx.x * 256 + threadIdx.x;  // NPAD*64 uints
    int f0 = (int)(((i >> 8) & 3) * 32 + ((i >> 6) & 3) * 8 + 2 * (i & 3));
    unsigned int h = H[i], l = L[i];
    float v0 = bf2f(h & 0xffffu) + bf2f(l & 0xffffu);
    float v1 = bf2f(h >> 16) + bf2f(l >> 16);
    v0 = fmaxf(fmaf(v0, scale[f0], shift[f0]), 0.f);
    v1 = fmaxf(fmaf(v1, scale[f0 + 1], shift[f0 + 1]), 0.f);
    unsigned short h0 = f2bf(v0), h1 = f2bf(v1);
    unsigned short l0 = f2bf(v0 - bf2f(h0)), l1 = f2bf(v1 - bf2f(h1));
    H[i] = (unsigned int)h0 | ((unsigned int)h1 << 16);
    L[i] = (unsigned int)l0 | ((unsigned int)l1 << 16);
}

// ---------------- pooling + decoder ----------------
__global__ __launch_bounds__(256) void k_pool(const float* __restrict__ encp,
                                              const float* __restrict__ eb,
                                              const int* __restrict__ gstart,
                                              const int* __restrict__ gcnt,
                                              float* __restrict__ pooled) {
    int g = blockIdx.x;
    int f = threadIdx.x;
    int s0 = gstart[g];
    int c = gcnt[g];
    float b = eb[f];
    float acc = 0.f;
    for (int i = 0; i < c; i++) {
        float v = encp[(size_t)(s0 + i) * ENCDIM + f] + b;
        acc += fmaxf(v, 0.f);
    }
    pooled[g * ENCDIM + f] = acc / fmaxf((float)c, 1.0f);
}

__global__ __launch_bounds__(128) void k_dec(const float* __restrict__ pooled,
                                             const float* __restrict__ W1,
                                             const float* __restrict__ b1,
                                             const float* __restrict__ W2,
                                             const float* __restrict__ b2,
                                             float* __restrict__ out) {
    int g = blockIdx.x;
    int j = threadIdx.x;
    const float* p = &pooled[g * ENCDIM];
    float acc = b1[j];
    for (int k = 0; k < ENCDIM; k++) acc = fmaf(p[k], W1[k * 128 + j], acc);
    float h = fmaxf(acc, 0.f) * W2[j];
    for (int off = 32; off; off >>= 1) h += __shfl_down(h, off);
    __shared__ float red[2];
    if ((j & 63) == 0) red[j >> 6] = h;
    __syncthreads();
    if (j == 0) out[g] = red[0] + red[1] + b2[0];
}

extern "C" void kernel_launch(void* const* d_in, const int* in_sizes, int n_in,
                              void* d_out, int out_size, void* d_ws, size_t ws_size,
                              hipStream_t stream) {
    const float* x = (const float*)d_in[0];
    const int* ei = (const int*)d_in[1];
    const int* src = ei;
    const int* dst = ei + N_EDGES;
    const int* batch = (const int*)d_in[2];
    const float* convW = (const float*)d_in[3];
    const float* convB = (const float*)d_in[4];
    const float* gamma = (const float*)d_in[5];
    const float* beta = (const float*)d_in[6];
    const float* encW = (const float*)d_in[7];
    const float* encB = (const float*)d_in[8];
    const float* dW1 = (const float*)d_in[9];
    const float* db1 = (const float*)d_in[10];
    const float* dW2 = (const float*)d_in[11];
    const float* db2 = (const float*)d_in[12];
    float* out = (float*)d_out;

    char* w = (char*)d_ws;
    auto alloc = [&](size_t bytes) {
        char* p = w;
        w += (bytes + 255) & ~(size_t)255;
        return p;
    };
    int* cnt = (int*)alloc((size_t)N_NODES * 4);
    int* rs = (int*)alloc((size_t)N_NODES * 4);
    int* cursor = (int*)alloc((size_t)N_NODES * 4);
    int* bsums = (int*)alloc(512 * 4);
    float* dinv = (float*)alloc((size_t)N_NODES * 4);
    int2* csr_ew = (int2*)alloc((size_t)N_EDGES * 8);
    unsigned short* Uh = (unsigned short*)alloc((size_t)NPAD * 128 * 2);
    unsigned short* Ul = (unsigned short*)alloc((size_t)NPAD * 128 * 2);
    float* B = (float*)alloc((size_t)NPAD * HDIM * 4);
    float* encp = (float*)alloc((size_t)NPAD * ENCDIM * 4);
    unsigned short* convWfh = (unsigned short*)alloc((size_t)NLAYERS * 16384 * 2);
    unsigned short* convWfl = (unsigned short*)alloc((size_t)NLAYERS * 16384 * 2);
    unsigned short* encWfh = (unsigned short*)alloc((size_t)NLAYERS * 32768 * 2);
    unsigned short* encWfl = (unsigned short*)alloc((size_t)NLAYERS * 32768 * 2);
    float* bnsum = (float*)alloc(128 * 4);
    float* bnsq = (float*)alloc(128 * 4);
    float* bnscale = (float*)alloc(128 * 4);
    float* bnshift = (float*)alloc(128 * 4);
    int* gcnt = (int*)alloc(256 * 4);
    int* gstart = (int*)alloc(256 * 4);
    float* pooled = (float*)alloc(256 * 256 * 4);

    // CSR build + degree normalization
    hipMemsetAsync(cnt, 0, (size_t)N_NODES * 4, stream);
    k_count<<<(N_EDGES + 255) / 256, 256, 0, stream>>>(dst, cnt);
    k_dinv<<<(N_NODES + 255) / 256, 256, 0, stream>>>(cnt, dinv);
    int nb = (N_NODES + 255) / 256;  // 391
    k_scan_block<<<nb, 256, 0, stream>>>(cnt, rs, bsums);
    k_scan_sums<<<1, 512, 0, stream>>>(bsums, nb);
    k_scan_add<<<nb, 256, 0, stream>>>(rs, bsums, cursor);
    k_scatter<<<(N_EDGES + 255) / 256, 256, 0, stream>>>(src, dst, dinv, cursor, csr_ew);
    k_gbounds<<<1, 256, 0, stream>>>(batch, gstart, gcnt);

    // weight fragment permute + split (tiny)
    for (int l = 0; l < NLAYERS; l++) {
        k_wfrag<<<8, 256, 0, stream>>>(convW + (size_t)l * 16384, 128, 8,
                                       convWfh + (size_t)l * 16384,
                                       convWfl + (size_t)l * 16384);
        k_wfrag<<<16, 256, 0, stream>>>(encW + (size_t)l * 128 * 256, 256, 16,
                                        encWfh + (size_t)l * 32768,
                                        encWfl + (size_t)l * 32768);
    }

    // x -> U pair, frag-ordered (pads zeroed)
    k_split_x<<<NPAD * 32 / 256, 256, 0, stream>>>((const float4*)x, Uh, Ul);

    for (int l = 0; l < NLAYERS; l++) {
        // hw = h @ convW_l
        k_mfma<0><<<dim3(NPAD / 128, 1), 256, 0, stream>>>(
            Uh, Ul, convWfh + (size_t)l * 16384, convWfl + (size_t)l * 16384, B, 128);
        // aggregate + bias -> U pair (frag-ordered), fused BN stats
        hipMemsetAsync(bnsum, 0, 128 * 4, stream);
        hipMemsetAsync(bnsq, 0, 128 * 4, stream);
        k_agg<<<N_NODES / 4, 256, 0, stream>>>((const float4*)B, rs, cnt, csr_ew, dinv,
                                               (const float4*)(convB + l * 128), Uh, Ul,
                                               bnsum, bnsq);
        k_bn_finalize<<<1, 128, 0, stream>>>(bnsum, bnsq, gamma + l * 128, beta + l * 128,
                                             bnscale, bnshift);
        k_bn_apply<<<NPAD * 64 / 256, 256, 0, stream>>>((unsigned int*)Uh,
                                                        (unsigned int*)Ul,
                                                        bnscale, bnshift);
        // encp (+)= h_l @ encW_l
        if (l == 0)
            k_mfma<0><<<dim3(NPAD / 128, 2), 256, 0, stream>>>(
                Uh, Ul, encWfh + (size_t)l * 32768, encWfl + (size_t)l * 32768, encp, 256);
        else
            k_mfma<1><<<dim3(NPAD / 128, 2), 256, 0, stream>>>(
                Uh, Ul, encWfh + (size_t)l * 32768, encWfl + (size_t)l * 32768, encp, 256);
    }

    // pooling + decoder
    k_pool<<<256, 256, 0, stream>>>(encp, encB, gstart, gcnt, pooled);
    k_dec<<<256, 128, 0, stream>>>(pooled, dW1, db1, dW2, db2, out);
}

// Round 5
// 1515.121 us; speedup vs baseline: 6.9661x; 6.9661x over previous
//
#include <hip/hip_runtime.h>
#include <hip/hip_bf16.h>

#define N_NODES 100000
#define NPAD    100096   // 782 * 128
#define N_EDGES 1600000
#define HDIM 128
#define NLAYERS 4
#define NGRAPH 256
#define ENCDIM 256
#define EPS_BN 1e-5f

typedef __attribute__((ext_vector_type(8))) short bf16x8;
typedef __attribute__((ext_vector_type(4))) float f32x4;

__device__ __forceinline__ unsigned short f2bf(float v) {
    unsigned int u = __float_as_uint(v);
    u += 0x7FFFu + ((u >> 16) & 1u);
    return (unsigned short)(u >> 16);
}
__device__ __forceinline__ float bf2f(unsigned int lo16) {
    return __uint_as_float(lo16 << 16);
}

// ---------------- CSR build ----------------
__global__ void k_count(const int* __restrict__ dst, int* __restrict__ cnt) {
    int e = blockIdx.x * 256 + threadIdx.x;
    if (e < N_EDGES) atomicAdd(&cnt[dst[e]], 1);
}

__global__ void k_dinv(const int* __restrict__ cnt, float* __restrict__ dinv) {
    int n = blockIdx.x * 256 + threadIdx.x;
    if (n < N_NODES) dinv[n] = rsqrtf((float)cnt[n] + 1.0f);
}

__global__ void k_scan_block(const int* __restrict__ cnt, int* __restrict__ excl,
                             int* __restrict__ bsums) {
    __shared__ int s[256];
    int t = threadIdx.x;
    int i = blockIdx.x * 256 + t;
    int v = (i < N_NODES) ? cnt[i] : 0;
    s[t] = v;
    __syncthreads();
    for (int off = 1; off < 256; off <<= 1) {
        int x = 0;
        if (t >= off) x = s[t - off];
        __syncthreads();
        if (t >= off) s[t] += x;
        __syncthreads();
    }
    if (i < N_NODES) excl[i] = s[t] - v;
    if (t == 255) bsums[blockIdx.x] = s[255];
}

__global__ void k_scan_sums(int* __restrict__ bsums, int nb) {
    __shared__ int s[512];
    int t = threadIdx.x;
    int v = (t < nb) ? bsums[t] : 0;
    s[t] = v;
    __syncthreads();
    for (int off = 1; off < 512; off <<= 1) {
        int x = 0;
        if (t >= off) x = s[t - off];
        __syncthreads();
        if (t >= off) s[t] += x;
        __syncthreads();
    }
    if (t < nb) bsums[t] = s[t] - v;
}

__global__ void k_scan_add(int* __restrict__ excl, const int* __restrict__ bsums,
                           int* __restrict__ cursor) {
    int i = blockIdx.x * 256 + threadIdx.x;
    if (i < N_NODES) {
        int v = excl[i] + bsums[blockIdx.x];
        excl[i] = v;
        cursor[i] = v;
    }
}

__global__ void k_scatter(const int* __restrict__ src, const int* __restrict__ dst,
                          const float* __restrict__ dinv, int* __restrict__ cursor,
                          int2* __restrict__ csr_ew) {
    int e = blockIdx.x * 256 + threadIdx.x;
    if (e < N_EDGES) {
        int d = dst[e];
        int s = src[e];
        int p = atomicAdd(&cursor[d], 1);
        int2 v;
        v.x = s;
        v.y = __float_as_int(dinv[s] * dinv[d]);
        csr_ew[p] = v;
    }
}

// ---------------- graph bounds via binary search (batch is sorted) ----------------
__global__ void k_gbounds(const int* __restrict__ batch, int* __restrict__ gstart,
                          int* __restrict__ gcnt) {
    __shared__ int s[257];
    int g = threadIdx.x;  // 256 threads
    int lo = 0, hi = N_NODES;
    while (lo < hi) {
        int mid = (lo + hi) >> 1;
        if (batch[mid] < g) lo = mid + 1; else hi = mid;
    }
    s[g] = lo;
    if (g == 255) s[256] = N_NODES;
    __syncthreads();
    gstart[g] = s[g];
    gcnt[g] = s[g + 1] - s[g];
}

// ---------------- weight -> MFMA B-fragment order, split hi/lo ----------------
// Frag layout: F[((nt*4 + ks)*64 + lane)*8 + j] = W[(ks*32 + (lane>>4)*8 + j)*ldw
//                                                   + nt*16 + (lane&15)]
__global__ void k_wfrag(const float* __restrict__ W, int ldw, int ntiles,
                        unsigned short* __restrict__ Fh, unsigned short* __restrict__ Fl) {
    int t = blockIdx.x * 256 + threadIdx.x;
    if (t >= ntiles * 256) return;
    int lane = t & 63, ks = (t >> 6) & 3, nt = t >> 8;
    int r16 = lane & 15, kq = lane >> 4;
    unsigned short h[8], l[8];
#pragma unroll
    for (int j = 0; j < 8; j++) {
        float w = W[(size_t)(ks * 32 + kq * 8 + j) * ldw + nt * 16 + r16];
        unsigned short hh = f2bf(w);
        h[j] = hh;
        l[j] = f2bf(w - bf2f(hh));
    }
    ((ushort4*)(Fh + (size_t)t * 8))[0] = make_ushort4(h[0], h[1], h[2], h[3]);
    ((ushort4*)(Fh + (size_t)t * 8))[1] = make_ushort4(h[4], h[5], h[6], h[7]);
    ((ushort4*)(Fl + (size_t)t * 8))[0] = make_ushort4(l[0], l[1], l[2], l[3]);
    ((ushort4*)(Fl + (size_t)t * 8))[1] = make_ushort4(l[4], l[5], l[6], l[7]);
}

// ---------------- x -> hi/lo bf16, row-major (pads zeroed) ----------------
__global__ __launch_bounds__(256) void k_split_x(const float4* __restrict__ x4,
                                                 ushort4* __restrict__ Uh4,
                                                 ushort4* __restrict__ Ul4) {
    size_t i = (size_t)blockIdx.x * 256 + threadIdx.x;  // NPAD*32 float4s
    size_t row = i >> 5;
    float4 v = make_float4(0.f, 0.f, 0.f, 0.f);
    if (row < N_NODES) v = x4[i];
    ushort4 h, l;
    h.x = f2bf(v.x); l.x = f2bf(v.x - bf2f(h.x));
    h.y = f2bf(v.y); l.y = f2bf(v.y - bf2f(h.y));
    h.z = f2bf(v.z); l.z = f2bf(v.z - bf2f(h.z));
    h.w = f2bf(v.w); l.w = f2bf(v.w - bf2f(h.w));
    Uh4[i] = h;
    Ul4[i] = l;
}

// ---------------- split-bf16 MFMA GEMM (row-major A) ----------------
template <int ACC>
__global__ __launch_bounds__(256) void k_mfma(const unsigned short* __restrict__ Ah,
                                              const unsigned short* __restrict__ Al,
                                              const unsigned short* __restrict__ Fh,
                                              const unsigned short* __restrict__ Fl,
                                              float* __restrict__ C, int ldc) {
    int lane = threadIdx.x & 63;
    int wid = threadIdx.x >> 6;
    int r16 = lane & 15, kq = lane >> 4;
    size_t mrow0 = (size_t)blockIdx.x * 128 + wid * 32;
    int colOff = blockIdx.y * 128;
    int ntBase = blockIdx.y * 8;

    bf16x8 ah[2][4], al[2][4];
#pragma unroll
    for (int mt = 0; mt < 2; mt++) {
        const unsigned short* pa = Ah + (mrow0 + mt * 16 + r16) * 128 + kq * 8;
        const unsigned short* pl = Al + (mrow0 + mt * 16 + r16) * 128 + kq * 8;
#pragma unroll
        for (int ks = 0; ks < 4; ks++) {
            ah[mt][ks] = *reinterpret_cast<const bf16x8*>(pa + ks * 32);
            al[mt][ks] = *reinterpret_cast<const bf16x8*>(pl + ks * 32);
        }
    }

    f32x4 acc[2][8];
#pragma unroll
    for (int mt = 0; mt < 2; mt++)
#pragma unroll
        for (int nt = 0; nt < 8; nt++) acc[mt][nt] = (f32x4){0.f, 0.f, 0.f, 0.f};

#pragma unroll
    for (int nt = 0; nt < 8; nt++) {
        const unsigned short* pbh = Fh + ((size_t)(ntBase + nt) * 4 * 64 + lane) * 8;
        const unsigned short* pbl = Fl + ((size_t)(ntBase + nt) * 4 * 64 + lane) * 8;
        bf16x8 bh[4], bl[4];
#pragma unroll
        for (int ks = 0; ks < 4; ks++) {
            bh[ks] = *reinterpret_cast<const bf16x8*>(pbh + ks * 512);
            bl[ks] = *reinterpret_cast<const bf16x8*>(pbl + ks * 512);
        }
#pragma unroll
        for (int mt = 0; mt < 2; mt++)
#pragma unroll
            for (int ks = 0; ks < 4; ks++) {
                acc[mt][nt] = __builtin_amdgcn_mfma_f32_16x16x32_bf16(ah[mt][ks], bl[ks],
                                                                     acc[mt][nt], 0, 0, 0);
                acc[mt][nt] = __builtin_amdgcn_mfma_f32_16x16x32_bf16(al[mt][ks], bh[ks],
                                                                     acc[mt][nt], 0, 0, 0);
                acc[mt][nt] = __builtin_amdgcn_mfma_f32_16x16x32_bf16(ah[mt][ks], bh[ks],
                                                                     acc[mt][nt], 0, 0, 0);
            }
    }

#pragma unroll
    for (int mt = 0; mt < 2; mt++)
#pragma unroll
        for (int nt = 0; nt < 8; nt++)
#pragma unroll
            for (int r = 0; r < 4; r++) {
                size_t row = mrow0 + mt * 16 + kq * 4 + r;
                float* cp = C + row * ldc + colOff + nt * 16 + r16;
                float v = acc[mt][nt][r];
                if (ACC) v += *cp;
                *cp = v;
            }
}

// ---------------- aggregation: U(pair) <- S * hw + bias ----------------
// 8 nodes/block; 32 lanes x float4 per node; unroll 8 -> 8 independent 16B
// gathers in flight per lane.
__global__ __launch_bounds__(256) void k_agg(const float4* __restrict__ hw4,
                                             const int* __restrict__ rs,
                                             const int* __restrict__ cnt,
                                             const int2* __restrict__ csr_ew,
                                             const float* __restrict__ dinv,
                                             const float4* __restrict__ bias4,
                                             unsigned short* __restrict__ Uh,
                                             unsigned short* __restrict__ Ul) {
    int n = blockIdx.x * 8 + (threadIdx.x >> 5);
    int lane = threadIdx.x & 31;
    if (n >= N_NODES) return;
    float d = dinv[n];
    float dd = d * d;
    float4 self = hw4[(size_t)n * 32 + lane];
    float4 b = bias4[lane];
    float4 acc;
    acc.x = fmaf(dd, self.x, b.x);
    acc.y = fmaf(dd, self.y, b.y);
    acc.z = fmaf(dd, self.z, b.z);
    acc.w = fmaf(dd, self.w, b.w);
    int s0 = rs[n];
    int c = cnt[n];
    int e = 0;
    for (; e + 8 <= c; e += 8) {
        int2 ee[8];
        float4 vv[8];
#pragma unroll
        for (int u = 0; u < 8; u++) ee[u] = csr_ew[s0 + e + u];
#pragma unroll
        for (int u = 0; u < 8; u++) vv[u] = hw4[(size_t)ee[u].x * 32 + lane];
#pragma unroll
        for (int u = 0; u < 8; u++) {
            float w = __int_as_float(ee[u].y);
            acc.x = fmaf(w, vv[u].x, acc.x);
            acc.y = fmaf(w, vv[u].y, acc.y);
            acc.z = fmaf(w, vv[u].z, acc.z);
            acc.w = fmaf(w, vv[u].w, acc.w);
        }
    }
    for (; e < c; e++) {
        int2 ee = csr_ew[s0 + e];
        float4 v = hw4[(size_t)ee.x * 32 + lane];
        float w = __int_as_float(ee.y);
        acc.x = fmaf(w, v.x, acc.x); acc.y = fmaf(w, v.y, acc.y);
        acc.z = fmaf(w, v.z, acc.z); acc.w = fmaf(w, v.w, acc.w);
    }
    ushort4 hv, lv;
    hv.x = f2bf(acc.x); lv.x = f2bf(acc.x - bf2f(hv.x));
    hv.y = f2bf(acc.y); lv.y = f2bf(acc.y - bf2f(hv.y));
    hv.z = f2bf(acc.z); lv.z = f2bf(acc.z - bf2f(hv.z));
    hv.w = f2bf(acc.w); lv.w = f2bf(acc.w - bf2f(hv.w));
    *(ushort4*)(Uh + (size_t)n * 128 + lane * 4) = hv;
    *(ushort4*)(Ul + (size_t)n * 128 + lane * 4) = lv;
}

// ---------------- BN on the hi/lo pair ----------------
__global__ __launch_bounds__(256) void k_bn_stats(const unsigned int* __restrict__ H,
                                                  const unsigned int* __restrict__ L,
                                                  float* __restrict__ sum,
                                                  float* __restrict__ sq) {
    int c = threadIdx.x & 63;   // uint column = features 2c, 2c+1
    int y = threadIdx.x >> 6;
    float s0 = 0.f, s1 = 0.f, q0 = 0.f, q1 = 0.f;
    for (size_t n = (size_t)blockIdx.x * 4 + y; n < N_NODES; n += (size_t)gridDim.x * 4) {
        unsigned int h = H[n * 64 + c], l = L[n * 64 + c];
        float v0 = bf2f(h & 0xffffu) + bf2f(l & 0xffffu);
        float v1 = bf2f(h >> 16) + bf2f(l >> 16);
        s0 += v0; q0 = fmaf(v0, v0, q0);
        s1 += v1; q1 = fmaf(v1, v1, q1);
    }
    __shared__ float ls[256][4];
    ls[threadIdx.x][0] = s0; ls[threadIdx.x][1] = s1;
    ls[threadIdx.x][2] = q0; ls[threadIdx.x][3] = q1;
    __syncthreads();
    if (y == 0) {
#pragma unroll
        for (int yy = 1; yy < 4; yy++) {
            s0 += ls[yy * 64 + c][0]; s1 += ls[yy * 64 + c][1];
            q0 += ls[yy * 64 + c][2]; q1 += ls[yy * 64 + c][3];
        }
        atomicAdd(&sum[2 * c], s0);
        atomicAdd(&sum[2 * c + 1], s1);
        atomicAdd(&sq[2 * c], q0);
        atomicAdd(&sq[2 * c + 1], q1);
    }
}

__global__ void k_bn_finalize(const float* __restrict__ sum, const float* __restrict__ sq,
                              const float* __restrict__ gamma, const float* __restrict__ beta,
                              float* __restrict__ scale, float* __restrict__ shift) {
    int f = threadIdx.x;
    float mu = sum[f] * (1.0f / N_NODES);
    float var = sq[f] * (1.0f / N_NODES) - mu * mu;
    float s = rsqrtf(var + EPS_BN) * gamma[f];
    scale[f] = s;
    shift[f] = beta[f] - mu * s;
}

__global__ __launch_bounds__(256) void k_bn_apply(unsigned int* __restrict__ H,
                                                  unsigned int* __restrict__ L,
                                                  const float* __restrict__ scale,
                                                  const float* __restrict__ shift) {
    size_t i = (size_t)blockIdx.x * 256 + threadIdx.x;  // N_NODES*64 uints
    int c = (int)(i & 63);
    unsigned int h = H[i], l = L[i];
    float v0 = bf2f(h & 0xffffu) + bf2f(l & 0xffffu);
    float v1 = bf2f(h >> 16) + bf2f(l >> 16);
    v0 = fmaxf(fmaf(v0, scale[2 * c], shift[2 * c]), 0.f);
    v1 = fmaxf(fmaf(v1, scale[2 * c + 1], shift[2 * c + 1]), 0.f);
    unsigned short h0 = f2bf(v0), h1 = f2bf(v1);
    unsigned short l0 = f2bf(v0 - bf2f(h0)), l1 = f2bf(v1 - bf2f(h1));
    H[i] = (unsigned int)h0 | ((unsigned int)h1 << 16);
    L[i] = (unsigned int)l0 | ((unsigned int)l1 << 16);
}

// ---------------- pooling + decoder ----------------
__global__ __launch_bounds__(256) void k_pool(const float* __restrict__ encp,
                                              const float* __restrict__ eb,
                                              const int* __restrict__ gstart,
                                              const int* __restrict__ gcnt,
                                              float* __restrict__ pooled) {
    int g = blockIdx.x;
    int f = threadIdx.x;
    int s0 = gstart[g];
    int c = gcnt[g];
    float b = eb[f];
    float acc = 0.f;
    for (int i = 0; i < c; i++) {
        float v = encp[(size_t)(s0 + i) * ENCDIM + f] + b;
        acc += fmaxf(v, 0.f);
    }
    pooled[g * ENCDIM + f] = acc / fmaxf((float)c, 1.0f);
}

__global__ __launch_bounds__(128) void k_dec(const float* __restrict__ pooled,
                                             const float* __restrict__ W1,
                                             const float* __restrict__ b1,
                                             const float* __restrict__ W2,
                                             const float* __restrict__ b2,
                                             float* __restrict__ out) {
    int g = blockIdx.x;
    int j = threadIdx.x;
    const float* p = &pooled[g * ENCDIM];
    float acc = b1[j];
    for (int k = 0; k < ENCDIM; k++) acc = fmaf(p[k], W1[k * 128 + j], acc);
    float h = fmaxf(acc, 0.f) * W2[j];
    for (int off = 32; off; off >>= 1) h += __shfl_down(h, off);
    __shared__ float red[2];
    if ((j & 63) == 0) red[j >> 6] = h;
    __syncthreads();
    if (j == 0) out[g] = red[0] + red[1] + b2[0];
}

extern "C" void kernel_launch(void* const* d_in, const int* in_sizes, int n_in,
                              void* d_out, int out_size, void* d_ws, size_t ws_size,
                              hipStream_t stream) {
    const float* x = (const float*)d_in[0];
    const int* ei = (const int*)d_in[1];
    const int* src = ei;
    const int* dst = ei + N_EDGES;
    const int* batch = (const int*)d_in[2];
    const float* convW = (const float*)d_in[3];
    const float* convB = (const float*)d_in[4];
    const float* gamma = (const float*)d_in[5];
    const float* beta = (const float*)d_in[6];
    const float* encW = (const float*)d_in[7];
    const float* encB = (const float*)d_in[8];
    const float* dW1 = (const float*)d_in[9];
    const float* db1 = (const float*)d_in[10];
    const float* dW2 = (const float*)d_in[11];
    const float* db2 = (const float*)d_in[12];
    float* out = (float*)d_out;

    char* w = (char*)d_ws;
    auto alloc = [&](size_t bytes) {
        char* p = w;
        w += (bytes + 255) & ~(size_t)255;
        return p;
    };
    int* cnt = (int*)alloc((size_t)N_NODES * 4);
    int* rs = (int*)alloc((size_t)N_NODES * 4);
    int* cursor = (int*)alloc((size_t)N_NODES * 4);
    int* bsums = (int*)alloc(512 * 4);
    float* dinv = (float*)alloc((size_t)N_NODES * 4);
    int2* csr_ew = (int2*)alloc((size_t)N_EDGES * 8);
    unsigned short* Uh = (unsigned short*)alloc((size_t)NPAD * 128 * 2);
    unsigned short* Ul = (unsigned short*)alloc((size_t)NPAD * 128 * 2);
    float* B = (float*)alloc((size_t)NPAD * HDIM * 4);
    float* encp = (float*)alloc((size_t)NPAD * ENCDIM * 4);
    unsigned short* convWfh = (unsigned short*)alloc((size_t)NLAYERS * 16384 * 2);
    unsigned short* convWfl = (unsigned short*)alloc((size_t)NLAYERS * 16384 * 2);
    unsigned short* encWfh = (unsigned short*)alloc((size_t)NLAYERS * 32768 * 2);
    unsigned short* encWfl = (unsigned short*)alloc((size_t)NLAYERS * 32768 * 2);
    float* bnsum = (float*)alloc(128 * 4);
    float* bnsq = (float*)alloc(128 * 4);
    float* bnscale = (float*)alloc(128 * 4);
    float* bnshift = (float*)alloc(128 * 4);
    int* gcnt = (int*)alloc(256 * 4);
    int* gstart = (int*)alloc(256 * 4);
    float* pooled = (float*)alloc(256 * 256 * 4);

    // CSR build + degree normalization
    hipMemsetAsync(cnt, 0, (size_t)N_NODES * 4, stream);
    k_count<<<(N_EDGES + 255) / 256, 256, 0, stream>>>(dst, cnt);
    k_dinv<<<(N_NODES + 255) / 256, 256, 0, stream>>>(cnt, dinv);
    int nb = (N_NODES + 255) / 256;  // 391
    k_scan_block<<<nb, 256, 0, stream>>>(cnt, rs, bsums);
    k_scan_sums<<<1, 512, 0, stream>>>(bsums, nb);
    k_scan_add<<<nb, 256, 0, stream>>>(rs, bsums, cursor);
    k_scatter<<<(N_EDGES + 255) / 256, 256, 0, stream>>>(src, dst, dinv, cursor, csr_ew);
    k_gbounds<<<1, 256, 0, stream>>>(batch, gstart, gcnt);

    // weight fragment permute + split (tiny)
    for (int l = 0; l < NLAYERS; l++) {
        k_wfrag<<<8, 256, 0, stream>>>(convW + (size_t)l * 16384, 128, 8,
                                       convWfh + (size_t)l * 16384,
                                       convWfl + (size_t)l * 16384);
        k_wfrag<<<16, 256, 0, stream>>>(encW + (size_t)l * 128 * 256, 256, 16,
                                        encWfh + (size_t)l * 32768,
                                        encWfl + (size_t)l * 32768);
    }

    // x -> U pair (pads zeroed)
    k_split_x<<<NPAD * 32 / 256, 256, 0, stream>>>((const float4*)x, (ushort4*)Uh,
                                                   (ushort4*)Ul);

    for (int l = 0; l < NLAYERS; l++) {
        // hw = h @ convW_l
        k_mfma<0><<<dim3(NPAD / 128, 1), 256, 0, stream>>>(
            Uh, Ul, convWfh + (size_t)l * 16384, convWfl + (size_t)l * 16384, B, 128);
        // aggregate + bias -> U pair
        k_agg<<<N_NODES / 8, 256, 0, stream>>>((const float4*)B, rs, cnt, csr_ew, dinv,
                                               (const float4*)(convB + l * 128), Uh, Ul);
        // BN + ReLU on U pair
        hipMemsetAsync(bnsum, 0, 128 * 4, stream);
        hipMemsetAsync(bnsq, 0, 128 * 4, stream);
        k_bn_stats<<<512, 256, 0, stream>>>((const unsigned int*)Uh,
                                            (const unsigned int*)Ul, bnsum, bnsq);
        k_bn_finalize<<<1, 128, 0, stream>>>(bnsum, bnsq, gamma + l * 128, beta + l * 128,
                                             bnscale, bnshift);
        k_bn_apply<<<N_NODES * 64 / 256, 256, 0, stream>>>((unsigned int*)Uh,
                                                           (unsigned int*)Ul,
                                                           bnscale, bnshift);
        // encp (+)= h_l @ encW_l
        if (l == 0)
            k_mfma<0><<<dim3(NPAD / 128, 2), 256, 0, stream>>>(
                Uh, Ul, encWfh + (size_t)l * 32768, encWfl + (size_t)l * 32768, encp, 256);
        else
            k_mfma<1><<<dim3(NPAD / 128, 2), 256, 0, stream>>>(
                Uh, Ul, encWfh + (size_t)l * 32768, encWfl + (size_t)l * 32768, encp, 256);
    }

    // pooling + decoder
    k_pool<<<256, 256, 0, stream>>>(encp, encB, gstart, gcnt, pooled);
    k_dec<<<256, 128, 0, stream>>>(pooled, dW1, db1, dW2, db2, out);
}

// Round 6
// 1427.681 us; speedup vs baseline: 7.3928x; 1.0612x over previous
//
#include <hip/hip_runtime.h>
#include <hip/hip_bf16.h>

#define N_NODES 100000
#define NPAD    100096   // 782 * 128
#define N_EDGES 1600000
#define HDIM 128
#define NLAYERS 4
#define NGRAPH 256
#define ENCDIM 256
#define EPS_BN 1e-5f

typedef __attribute__((ext_vector_type(8))) short bf16x8;
typedef __attribute__((ext_vector_type(4))) float f32x4;

__device__ __forceinline__ unsigned short f2bf(float v) {
    unsigned int u = __float_as_uint(v);
    u += 0x7FFFu + ((u >> 16) & 1u);
    return (unsigned short)(u >> 16);
}
__device__ __forceinline__ float bf2f(unsigned int lo16) {
    return __uint_as_float(lo16 << 16);
}

// ---------------- CSR build ----------------
__global__ void k_count(const int* __restrict__ dst, int* __restrict__ cnt) {
    int e = blockIdx.x * 256 + threadIdx.x;
    if (e < N_EDGES) atomicAdd(&cnt[dst[e]], 1);
}

__global__ void k_dinv(const int* __restrict__ cnt, float* __restrict__ dinv) {
    int n = blockIdx.x * 256 + threadIdx.x;
    if (n < N_NODES) dinv[n] = rsqrtf((float)cnt[n] + 1.0f);
}

__global__ void k_scan_block(const int* __restrict__ cnt, int* __restrict__ excl,
                             int* __restrict__ bsums) {
    __shared__ int s[256];
    int t = threadIdx.x;
    int i = blockIdx.x * 256 + t;
    int v = (i < N_NODES) ? cnt[i] : 0;
    s[t] = v;
    __syncthreads();
    for (int off = 1; off < 256; off <<= 1) {
        int x = 0;
        if (t >= off) x = s[t - off];
        __syncthreads();
        if (t >= off) s[t] += x;
        __syncthreads();
    }
    if (i < N_NODES) excl[i] = s[t] - v;
    if (t == 255) bsums[blockIdx.x] = s[255];
}

__global__ void k_scan_sums(int* __restrict__ bsums, int nb) {
    __shared__ int s[512];
    int t = threadIdx.x;
    int v = (t < nb) ? bsums[t] : 0;
    s[t] = v;
    __syncthreads();
    for (int off = 1; off < 512; off <<= 1) {
        int x = 0;
        if (t >= off) x = s[t - off];
        __syncthreads();
        if (t >= off) s[t] += x;
        __syncthreads();
    }
    if (t < nb) bsums[t] = s[t] - v;
}

__global__ void k_scan_add(int* __restrict__ excl, const int* __restrict__ bsums,
                           int* __restrict__ cursor) {
    int i = blockIdx.x * 256 + threadIdx.x;
    if (i < N_NODES) {
        int v = excl[i] + bsums[blockIdx.x];
        excl[i] = v;
        cursor[i] = v;
    }
}

__global__ void k_scatter(const int* __restrict__ src, const int* __restrict__ dst,
                          const float* __restrict__ dinv, int* __restrict__ cursor,
                          int2* __restrict__ csr_ew) {
    int e = blockIdx.x * 256 + threadIdx.x;
    if (e < N_EDGES) {
        int d = dst[e];
        int s = src[e];
        int p = atomicAdd(&cursor[d], 1);
        int2 v;
        v.x = s;
        v.y = __float_as_int(dinv[s] * dinv[d]);
        csr_ew[p] = v;
    }
}

// ---------------- graph bounds via binary search (batch is sorted) ----------------
__global__ void k_gbounds(const int* __restrict__ batch, int* __restrict__ gstart,
                          int* __restrict__ gcnt) {
    __shared__ int s[257];
    int g = threadIdx.x;  // 256 threads
    int lo = 0, hi = N_NODES;
    while (lo < hi) {
        int mid = (lo + hi) >> 1;
        if (batch[mid] < g) lo = mid + 1; else hi = mid;
    }
    s[g] = lo;
    if (g == 255) s[256] = N_NODES;
    __syncthreads();
    gstart[g] = s[g];
    gcnt[g] = s[g + 1] - s[g];
}

// ---------------- weight -> MFMA B-fragment order, split hi/lo ----------------
// F[((nt*4 + ks)*64 + lane)*8 + j] = W[(ks*32 + (lane>>4)*8 + j)*ldw + nt*16 + (lane&15)]
__global__ void k_wfrag(const float* __restrict__ W, int ldw, int ntiles,
                        unsigned short* __restrict__ Fh, unsigned short* __restrict__ Fl) {
    int t = blockIdx.x * 256 + threadIdx.x;
    if (t >= ntiles * 256) return;
    int lane = t & 63, ks = (t >> 6) & 3, nt = t >> 8;
    int r16 = lane & 15, kq = lane >> 4;
    unsigned short h[8], l[8];
#pragma unroll
    for (int j = 0; j < 8; j++) {
        float w = W[(size_t)(ks * 32 + kq * 8 + j) * ldw + nt * 16 + r16];
        unsigned short hh = f2bf(w);
        h[j] = hh;
        l[j] = f2bf(w - bf2f(hh));
    }
    ((ushort4*)(Fh + (size_t)t * 8))[0] = make_ushort4(h[0], h[1], h[2], h[3]);
    ((ushort4*)(Fh + (size_t)t * 8))[1] = make_ushort4(h[4], h[5], h[6], h[7]);
    ((ushort4*)(Fl + (size_t)t * 8))[0] = make_ushort4(l[0], l[1], l[2], l[3]);
    ((ushort4*)(Fl + (size_t)t * 8))[1] = make_ushort4(l[4], l[5], l[6], l[7]);
}

// ---------------- split-bf16 MFMA GEMM, fp32 A with optional fused BN+ReLU ------
// A is [*, 128] fp32 (only rows < N_NODES valid). BN: v = relu(v*scale[f]+shift[f])
// applied in-register before the hi/lo split.
template <int ACC, int BN>
__global__ __launch_bounds__(256) void k_mfma(const float* __restrict__ A,
                                              const unsigned short* __restrict__ Fh,
                                              const unsigned short* __restrict__ Fl,
                                              const float* __restrict__ scale,
                                              const float* __restrict__ shift,
                                              float* __restrict__ C, int ldc) {
    int lane = threadIdx.x & 63;
    int wid = threadIdx.x >> 6;
    int r16 = lane & 15, kq = lane >> 4;
    size_t mrow0 = (size_t)blockIdx.x * 128 + wid * 32;
    int colOff = blockIdx.y * 128;
    int ntBase = blockIdx.y * 8;

    float4 sc[4][2], sh[4][2];
    if (BN) {
#pragma unroll
        for (int ks = 0; ks < 4; ks++) {
            int f0 = ks * 32 + kq * 8;
            sc[ks][0] = *(const float4*)&scale[f0];
            sc[ks][1] = *(const float4*)&scale[f0 + 4];
            sh[ks][0] = *(const float4*)&shift[f0];
            sh[ks][1] = *(const float4*)&shift[f0 + 4];
        }
    }

    bf16x8 ah[2][4], al[2][4];
#pragma unroll
    for (int mt = 0; mt < 2; mt++) {
        size_t row = mrow0 + mt * 16 + r16;
        bool ok = row < N_NODES;
        const float* pa = A + row * 128 + kq * 8;
#pragma unroll
        for (int ks = 0; ks < 4; ks++) {
            float4 v0 = make_float4(0.f, 0.f, 0.f, 0.f);
            float4 v1 = make_float4(0.f, 0.f, 0.f, 0.f);
            if (ok) {
                v0 = *(const float4*)(pa + ks * 32);
                v1 = *(const float4*)(pa + ks * 32 + 4);
            }
            if (BN) {
                v0.x = fmaxf(fmaf(v0.x, sc[ks][0].x, sh[ks][0].x), 0.f);
                v0.y = fmaxf(fmaf(v0.y, sc[ks][0].y, sh[ks][0].y), 0.f);
                v0.z = fmaxf(fmaf(v0.z, sc[ks][0].z, sh[ks][0].z), 0.f);
                v0.w = fmaxf(fmaf(v0.w, sc[ks][0].w, sh[ks][0].w), 0.f);
                v1.x = fmaxf(fmaf(v1.x, sc[ks][1].x, sh[ks][1].x), 0.f);
                v1.y = fmaxf(fmaf(v1.y, sc[ks][1].y, sh[ks][1].y), 0.f);
                v1.z = fmaxf(fmaf(v1.z, sc[ks][1].z, sh[ks][1].z), 0.f);
                v1.w = fmaxf(fmaf(v1.w, sc[ks][1].w, sh[ks][1].w), 0.f);
                if (!ok) {
                    v0 = make_float4(0.f, 0.f, 0.f, 0.f);
                    v1 = make_float4(0.f, 0.f, 0.f, 0.f);
                }
            }
            float vv[8] = {v0.x, v0.y, v0.z, v0.w, v1.x, v1.y, v1.z, v1.w};
            bf16x8 hv, lv;
#pragma unroll
            for (int j = 0; j < 8; j++) {
                unsigned short hh = f2bf(vv[j]);
                hv[j] = (short)hh;
                lv[j] = (short)f2bf(vv[j] - bf2f(hh));
            }
            ah[mt][ks] = hv;
            al[mt][ks] = lv;
        }
    }

    f32x4 acc[2][8];
#pragma unroll
    for (int mt = 0; mt < 2; mt++)
#pragma unroll
        for (int nt = 0; nt < 8; nt++) acc[mt][nt] = (f32x4){0.f, 0.f, 0.f, 0.f};

#pragma unroll
    for (int nt = 0; nt < 8; nt++) {
        const unsigned short* pbh = Fh + ((size_t)(ntBase + nt) * 4 * 64 + lane) * 8;
        const unsigned short* pbl = Fl + ((size_t)(ntBase + nt) * 4 * 64 + lane) * 8;
        bf16x8 bh[4], bl[4];
#pragma unroll
        for (int ks = 0; ks < 4; ks++) {
            bh[ks] = *reinterpret_cast<const bf16x8*>(pbh + ks * 512);
            bl[ks] = *reinterpret_cast<const bf16x8*>(pbl + ks * 512);
        }
#pragma unroll
        for (int mt = 0; mt < 2; mt++)
#pragma unroll
            for (int ks = 0; ks < 4; ks++) {
                acc[mt][nt] = __builtin_amdgcn_mfma_f32_16x16x32_bf16(ah[mt][ks], bl[ks],
                                                                     acc[mt][nt], 0, 0, 0);
                acc[mt][nt] = __builtin_amdgcn_mfma_f32_16x16x32_bf16(al[mt][ks], bh[ks],
                                                                     acc[mt][nt], 0, 0, 0);
                acc[mt][nt] = __builtin_amdgcn_mfma_f32_16x16x32_bf16(ah[mt][ks], bh[ks],
                                                                     acc[mt][nt], 0, 0, 0);
            }
    }

#pragma unroll
    for (int mt = 0; mt < 2; mt++)
#pragma unroll
        for (int nt = 0; nt < 8; nt++)
#pragma unroll
            for (int r = 0; r < 4; r++) {
                size_t row = mrow0 + mt * 16 + kq * 4 + r;
                float* cp = C + row * ldc + colOff + nt * 16 + r16;
                float v = acc[mt][nt][r];
                if (ACC) v += *cp;
                *cp = v;
            }
}

// ---------------- aggregation: Uf <- S * hw + bias (fp32 out) ----------------
__global__ __launch_bounds__(256) void k_agg(const float4* __restrict__ hw4,
                                             const int* __restrict__ rs,
                                             const int* __restrict__ cnt,
                                             const int2* __restrict__ csr_ew,
                                             const float* __restrict__ dinv,
                                             const float4* __restrict__ bias4,
                                             float4* __restrict__ Uf4) {
    int n = blockIdx.x * 8 + (threadIdx.x >> 5);
    int lane = threadIdx.x & 31;
    if (n >= N_NODES) return;
    float d = dinv[n];
    float dd = d * d;
    float4 self = hw4[(size_t)n * 32 + lane];
    float4 b = bias4[lane];
    float4 acc;
    acc.x = fmaf(dd, self.x, b.x);
    acc.y = fmaf(dd, self.y, b.y);
    acc.z = fmaf(dd, self.z, b.z);
    acc.w = fmaf(dd, self.w, b.w);
    int s0 = rs[n];
    int c = cnt[n];
    int e = 0;
    for (; e + 8 <= c; e += 8) {
        int2 ee[8];
        float4 vv[8];
#pragma unroll
        for (int u = 0; u < 8; u++) ee[u] = csr_ew[s0 + e + u];
#pragma unroll
        for (int u = 0; u < 8; u++) vv[u] = hw4[(size_t)ee[u].x * 32 + lane];
#pragma unroll
        for (int u = 0; u < 8; u++) {
            float w = __int_as_float(ee[u].y);
            acc.x = fmaf(w, vv[u].x, acc.x);
            acc.y = fmaf(w, vv[u].y, acc.y);
            acc.z = fmaf(w, vv[u].z, acc.z);
            acc.w = fmaf(w, vv[u].w, acc.w);
        }
    }
    for (; e < c; e++) {
        int2 ee = csr_ew[s0 + e];
        float4 v = hw4[(size_t)ee.x * 32 + lane];
        float w = __int_as_float(ee.y);
        acc.x = fmaf(w, v.x, acc.x); acc.y = fmaf(w, v.y, acc.y);
        acc.z = fmaf(w, v.z, acc.z); acc.w = fmaf(w, v.w, acc.w);
    }
    Uf4[(size_t)n * 32 + lane] = acc;
}

// ---------------- BN stats on fp32 Uf ----------------
__global__ __launch_bounds__(256) void k_bn_stats(const float4* __restrict__ Uf4,
                                                  float* __restrict__ sum,
                                                  float* __restrict__ sq) {
    int c4 = threadIdx.x & 31;  // float4 column = features 4*c4..4*c4+3
    int y = threadIdx.x >> 5;   // 8 row-groups
    float4 s = make_float4(0.f, 0.f, 0.f, 0.f);
    float4 q = make_float4(0.f, 0.f, 0.f, 0.f);
    for (size_t n = (size_t)blockIdx.x * 8 + y; n < N_NODES; n += (size_t)gridDim.x * 8) {
        float4 v = Uf4[n * 32 + c4];
        s.x += v.x; s.y += v.y; s.z += v.z; s.w += v.w;
        q.x = fmaf(v.x, v.x, q.x); q.y = fmaf(v.y, v.y, q.y);
        q.z = fmaf(v.z, v.z, q.z); q.w = fmaf(v.w, v.w, q.w);
    }
    __shared__ float4 ls[256], lq[256];
    ls[threadIdx.x] = s;
    lq[threadIdx.x] = q;
    __syncthreads();
    if (y == 0) {
#pragma unroll
        for (int yy = 1; yy < 8; yy++) {
            float4 a = ls[yy * 32 + c4], b = lq[yy * 32 + c4];
            s.x += a.x; s.y += a.y; s.z += a.z; s.w += a.w;
            q.x += b.x; q.y += b.y; q.z += b.z; q.w += b.w;
        }
        atomicAdd(&sum[c4 * 4 + 0], s.x);
        atomicAdd(&sum[c4 * 4 + 1], s.y);
        atomicAdd(&sum[c4 * 4 + 2], s.z);
        atomicAdd(&sum[c4 * 4 + 3], s.w);
        atomicAdd(&sq[c4 * 4 + 0], q.x);
        atomicAdd(&sq[c4 * 4 + 1], q.y);
        atomicAdd(&sq[c4 * 4 + 2], q.z);
        atomicAdd(&sq[c4 * 4 + 3], q.w);
    }
}

__global__ void k_bn_finalize(const float* __restrict__ sum, const float* __restrict__ sq,
                              const float* __restrict__ gamma, const float* __restrict__ beta,
                              float* __restrict__ scale, float* __restrict__ shift) {
    int f = threadIdx.x;
    float mu = sum[f] * (1.0f / N_NODES);
    float var = sq[f] * (1.0f / N_NODES) - mu * mu;
    float s = rsqrtf(var + EPS_BN) * gamma[f];
    scale[f] = s;
    shift[f] = beta[f] - mu * s;
}

// ---------------- pooling + decoder ----------------
__global__ __launch_bounds__(256) void k_pool_part(const float* __restrict__ encp,
                                                   const float* __restrict__ eb,
                                                   const int* __restrict__ gstart,
                                                   const int* __restrict__ gcnt,
                                                   float* __restrict__ psum) {
    int g = blockIdx.x >> 3;
    int slice = blockIdx.x & 7;
    int f = threadIdx.x;
    int s0 = gstart[g];
    int c = gcnt[g];
    float b = eb[f];
    float acc = 0.f;
    for (int i = slice; i < c; i += 8)
        acc += fmaxf(encp[(size_t)(s0 + i) * ENCDIM + f] + b, 0.f);
    atomicAdd(&psum[g * ENCDIM + f], acc);
}

__global__ void k_pool_fin(const float* __restrict__ psum, const int* __restrict__ gcnt,
                           float* __restrict__ pooled) {
    int i = blockIdx.x * 256 + threadIdx.x;  // 65536
    int g = i >> 8;
    pooled[i] = psum[i] / fmaxf((float)gcnt[g], 1.0f);
}

__global__ __launch_bounds__(128) void k_dec(const float* __restrict__ pooled,
                                             const float* __restrict__ W1,
                                             const float* __restrict__ b1,
                                             const float* __restrict__ W2,
                                             const float* __restrict__ b2,
                                             float* __restrict__ out) {
    int g = blockIdx.x;
    int j = threadIdx.x;
    const float* p = &pooled[g * ENCDIM];
    float acc = b1[j];
    for (int k = 0; k < ENCDIM; k++) acc = fmaf(p[k], W1[k * 128 + j], acc);
    float h = fmaxf(acc, 0.f) * W2[j];
    for (int off = 32; off; off >>= 1) h += __shfl_down(h, off);
    __shared__ float red[2];
    if ((j & 63) == 0) red[j >> 6] = h;
    __syncthreads();
    if (j == 0) out[g] = red[0] + red[1] + b2[0];
}

extern "C" void kernel_launch(void* const* d_in, const int* in_sizes, int n_in,
                              void* d_out, int out_size, void* d_ws, size_t ws_size,
                              hipStream_t stream) {
    const float* x = (const float*)d_in[0];
    const int* ei = (const int*)d_in[1];
    const int* src = ei;
    const int* dst = ei + N_EDGES;
    const int* batch = (const int*)d_in[2];
    const float* convW = (const float*)d_in[3];
    const float* convB = (const float*)d_in[4];
    const float* gamma = (const float*)d_in[5];
    const float* beta = (const float*)d_in[6];
    const float* encW = (const float*)d_in[7];
    const float* encB = (const float*)d_in[8];
    const float* dW1 = (const float*)d_in[9];
    const float* db1 = (const float*)d_in[10];
    const float* dW2 = (const float*)d_in[11];
    const float* db2 = (const float*)d_in[12];
    float* out = (float*)d_out;

    char* w = (char*)d_ws;
    auto alloc = [&](size_t bytes) {
        char* p = w;
        w += (bytes + 255) & ~(size_t)255;
        return p;
    };
    int* cnt = (int*)alloc((size_t)N_NODES * 4);
    int* rs = (int*)alloc((size_t)N_NODES * 4);
    int* cursor = (int*)alloc((size_t)N_NODES * 4);
    int* bsums = (int*)alloc(512 * 4);
    float* dinv = (float*)alloc((size_t)N_NODES * 4);
    int2* csr_ew = (int2*)alloc((size_t)N_EDGES * 8);
    float* Uf = (float*)alloc((size_t)N_NODES * HDIM * 4);      // raw agg out (fp32)
    float* B = (float*)alloc((size_t)NPAD * HDIM * 4);          // hw fp32
    float* encp = (float*)alloc((size_t)NPAD * ENCDIM * 4);     // encoder pre-act
    unsigned short* convWfh = (unsigned short*)alloc((size_t)NLAYERS * 16384 * 2);
    unsigned short* convWfl = (unsigned short*)alloc((size_t)NLAYERS * 16384 * 2);
    unsigned short* encWfh = (unsigned short*)alloc((size_t)NLAYERS * 32768 * 2);
    unsigned short* encWfl = (unsigned short*)alloc((size_t)NLAYERS * 32768 * 2);
    float* bnsum = (float*)alloc(128 * 4);
    float* bnsq = (float*)alloc(128 * 4);
    float* bnscale = (float*)alloc(128 * 4);
    float* bnshift = (float*)alloc(128 * 4);
    int* gcnt = (int*)alloc(256 * 4);
    int* gstart = (int*)alloc(256 * 4);
    float* psum = (float*)alloc(256 * 256 * 4);
    float* pooled = (float*)alloc(256 * 256 * 4);

    // CSR build + degree normalization
    hipMemsetAsync(cnt, 0, (size_t)N_NODES * 4, stream);
    k_count<<<(N_EDGES + 255) / 256, 256, 0, stream>>>(dst, cnt);
    k_dinv<<<(N_NODES + 255) / 256, 256, 0, stream>>>(cnt, dinv);
    int nb = (N_NODES + 255) / 256;  // 391
    k_scan_block<<<nb, 256, 0, stream>>>(cnt, rs, bsums);
    k_scan_sums<<<1, 512, 0, stream>>>(bsums, nb);
    k_scan_add<<<nb, 256, 0, stream>>>(rs, bsums, cursor);
    k_scatter<<<(N_EDGES + 255) / 256, 256, 0, stream>>>(src, dst, dinv, cursor, csr_ew);
    k_gbounds<<<1, 256, 0, stream>>>(batch, gstart, gcnt);

    // weight fragment permute + split (tiny)
    for (int l = 0; l < NLAYERS; l++) {
        k_wfrag<<<8, 256, 0, stream>>>(convW + (size_t)l * 16384, 128, 8,
                                       convWfh + (size_t)l * 16384,
                                       convWfl + (size_t)l * 16384);
        k_wfrag<<<16, 256, 0, stream>>>(encW + (size_t)l * 128 * 256, 256, 16,
                                        encWfh + (size_t)l * 32768,
                                        encWfl + (size_t)l * 32768);
    }

    for (int l = 0; l < NLAYERS; l++) {
        // hw = h @ convW_l  (h = x for l=0, else BN_{l-1}(Uf) fused in-register)
        if (l == 0)
            k_mfma<0, 0><<<dim3(NPAD / 128, 1), 256, 0, stream>>>(
                x, convWfh + (size_t)l * 16384, convWfl + (size_t)l * 16384,
                nullptr, nullptr, B, 128);
        else
            k_mfma<0, 1><<<dim3(NPAD / 128, 1), 256, 0, stream>>>(
                Uf, convWfh + (size_t)l * 16384, convWfl + (size_t)l * 16384,
                bnscale, bnshift, B, 128);
        // aggregate + bias -> Uf (raw, fp32)
        k_agg<<<N_NODES / 8, 256, 0, stream>>>((const float4*)B, rs, cnt, csr_ew, dinv,
                                               (const float4*)(convB + l * 128),
                                               (float4*)Uf);
        // BN stats
        hipMemsetAsync(bnsum, 0, 128 * 4, stream);
        hipMemsetAsync(bnsq, 0, 128 * 4, stream);
        k_bn_stats<<<512, 256, 0, stream>>>((const float4*)Uf, bnsum, bnsq);
        k_bn_finalize<<<1, 128, 0, stream>>>(bnsum, bnsq, gamma + l * 128, beta + l * 128,
                                             bnscale, bnshift);
        // encp (+)= BN_l(Uf) @ encW_l  (BN fused)
        if (l == 0)
            k_mfma<0, 1><<<dim3(NPAD / 128, 2), 256, 0, stream>>>(
                Uf, encWfh + (size_t)l * 32768, encWfl + (size_t)l * 32768,
                bnscale, bnshift, encp, 256);
        else
            k_mfma<1, 1><<<dim3(NPAD / 128, 2), 256, 0, stream>>>(
                Uf, encWfh + (size_t)l * 32768, encWfl + (size_t)l * 32768,
                bnscale, bnshift, encp, 256);
    }

    // pooling + decoder
    hipMemsetAsync(psum, 0, 256 * 256 * 4, stream);
    k_pool_part<<<NGRAPH * 8, 256, 0, stream>>>(encp, encB, gstart, gcnt, psum);
    k_pool_fin<<<256, 256, 0, stream>>>(psum, gcnt, pooled);
    k_dec<<<256, 128, 0, stream>>>(pooled, dW1, db1, dW2, db2, out);
}

// Round 8
// 1415.616 us; speedup vs baseline: 7.4558x; 1.0085x over previous
//
#include <hip/hip_runtime.h>
#include <hip/hip_bf16.h>

#define N_NODES 100000
#define NPAD    100096   // 782 * 128
#define N_EDGES 1600000
#define HDIM 128
#define NLAYERS 4
#define NGRAPH 256
#define ENCDIM 256
#define EPS_BN 1e-5f

typedef __attribute__((ext_vector_type(8))) short bf16x8;
typedef __attribute__((ext_vector_type(4))) float f32x4;

__device__ __forceinline__ unsigned short f2bf(float v) {
    unsigned int u = __float_as_uint(v);
    u += 0x7FFFu + ((u >> 16) & 1u);
    return (unsigned short)(u >> 16);
}
__device__ __forceinline__ float bf2f(unsigned int lo16) {
    return __uint_as_float(lo16 << 16);
}

// ---------------- CSR build ----------------
__global__ void k_count(const int* __restrict__ dst, int* __restrict__ cnt) {
    int e = blockIdx.x * 256 + threadIdx.x;
    if (e < N_EDGES) atomicAdd(&cnt[dst[e]], 1);
}

__global__ void k_dinv(const int* __restrict__ cnt, float* __restrict__ dinv) {
    int n = blockIdx.x * 256 + threadIdx.x;
    if (n < N_NODES) dinv[n] = rsqrtf((float)cnt[n] + 1.0f);
}

__global__ void k_scan_block(const int* __restrict__ cnt, int* __restrict__ excl,
                             int* __restrict__ bsums) {
    __shared__ int s[256];
    int t = threadIdx.x;
    int i = blockIdx.x * 256 + t;
    int v = (i < N_NODES) ? cnt[i] : 0;
    s[t] = v;
    __syncthreads();
    for (int off = 1; off < 256; off <<= 1) {
        int x = 0;
        if (t >= off) x = s[t - off];
        __syncthreads();
        if (t >= off) s[t] += x;
        __syncthreads();
    }
    if (i < N_NODES) excl[i] = s[t] - v;
    if (t == 255) bsums[blockIdx.x] = s[255];
}

__global__ void k_scan_sums(int* __restrict__ bsums, int nb) {
    __shared__ int s[512];
    int t = threadIdx.x;
    int v = (t < nb) ? bsums[t] : 0;
    s[t] = v;
    __syncthreads();
    for (int off = 1; off < 512; off <<= 1) {
        int x = 0;
        if (t >= off) x = s[t - off];
        __syncthreads();
        if (t >= off) s[t] += x;
        __syncthreads();
    }
    if (t < nb) bsums[t] = s[t] - v;
}

__global__ void k_scan_add(int* __restrict__ excl, const int* __restrict__ bsums,
                           int* __restrict__ cursor) {
    int i = blockIdx.x * 256 + threadIdx.x;
    if (i < N_NODES) {
        int v = excl[i] + bsums[blockIdx.x];
        excl[i] = v;
        cursor[i] = v;
    }
}

__global__ void k_scatter(const int* __restrict__ src, const int* __restrict__ dst,
                          const float* __restrict__ dinv, int* __restrict__ cursor,
                          int2* __restrict__ csr_ew) {
    int e = blockIdx.x * 256 + threadIdx.x;
    if (e < N_EDGES) {
        int d = dst[e];
        int s = src[e];
        int p = atomicAdd(&cursor[d], 1);
        int2 v;
        v.x = s;
        v.y = __float_as_int(dinv[s] * dinv[d]);
        csr_ew[p] = v;
    }
}

// ---------------- graph bounds via binary search (batch is sorted) ----------------
__global__ void k_gbounds(const int* __restrict__ batch, int* __restrict__ gstart,
                          int* __restrict__ gcnt) {
    __shared__ int s[257];
    int g = threadIdx.x;  // 256 threads
    int lo = 0, hi = N_NODES;
    while (lo < hi) {
        int mid = (lo + hi) >> 1;
        if (batch[mid] < g) lo = mid + 1; else hi = mid;
    }
    s[g] = lo;
    if (g == 255) s[256] = N_NODES;
    __syncthreads();
    gstart[g] = s[g];
    gcnt[g] = s[g + 1] - s[g];
}

// ---------------- weight -> MFMA B-fragment order, split hi/lo ----------------
// F[((nt*4 + ks)*64 + lane)*8 + j] = W[(ks*32 + (lane>>4)*8 + j)*ldw + nt*16 + (lane&15)]
__global__ void k_wfrag(const float* __restrict__ W, int ldw, int ntiles,
                        unsigned short* __restrict__ Fh, unsigned short* __restrict__ Fl) {
    int t = blockIdx.x * 256 + threadIdx.x;
    if (t >= ntiles * 256) return;
    int lane = t & 63, ks = (t >> 6) & 3, nt = t >> 8;
    int r16 = lane & 15, kq = lane >> 4;
    unsigned short h[8], l[8];
#pragma unroll
    for (int j = 0; j < 8; j++) {
        float w = W[(size_t)(ks * 32 + kq * 8 + j) * ldw + nt * 16 + r16];
        unsigned short hh = f2bf(w);
        h[j] = hh;
        l[j] = f2bf(w - bf2f(hh));
    }
    ((ushort4*)(Fh + (size_t)t * 8))[0] = make_ushort4(h[0], h[1], h[2], h[3]);
    ((ushort4*)(Fh + (size_t)t * 8))[1] = make_ushort4(h[4], h[5], h[6], h[7]);
    ((ushort4*)(Fl + (size_t)t * 8))[0] = make_ushort4(l[0], l[1], l[2], l[3]);
    ((ushort4*)(Fl + (size_t)t * 8))[1] = make_ushort4(l[4], l[5], l[6], l[7]);
}

// ---------------- helper: load+BN+split one A fragment group ----------------
__device__ __forceinline__ void load_a_frag(const float* __restrict__ A, size_t row,
                                            bool ok, int kq, int ks,
                                            const float* __restrict__ scale,
                                            const float* __restrict__ shift, int useBN,
                                            bf16x8& hv_out, bf16x8& lv_out) {
    float4 v0 = make_float4(0.f, 0.f, 0.f, 0.f);
    float4 v1 = make_float4(0.f, 0.f, 0.f, 0.f);
    if (ok) {
        const float* pa = A + row * 128 + kq * 8 + ks * 32;
        v0 = *(const float4*)pa;
        v1 = *(const float4*)(pa + 4);
    }
    if (useBN) {
        int f0 = ks * 32 + kq * 8;
        float4 sc0 = *(const float4*)&scale[f0];
        float4 sc1 = *(const float4*)&scale[f0 + 4];
        float4 sh0 = *(const float4*)&shift[f0];
        float4 sh1 = *(const float4*)&shift[f0 + 4];
        v0.x = fmaxf(fmaf(v0.x, sc0.x, sh0.x), 0.f);
        v0.y = fmaxf(fmaf(v0.y, sc0.y, sh0.y), 0.f);
        v0.z = fmaxf(fmaf(v0.z, sc0.z, sh0.z), 0.f);
        v0.w = fmaxf(fmaf(v0.w, sc0.w, sh0.w), 0.f);
        v1.x = fmaxf(fmaf(v1.x, sc1.x, sh1.x), 0.f);
        v1.y = fmaxf(fmaf(v1.y, sc1.y, sh1.y), 0.f);
        v1.z = fmaxf(fmaf(v1.z, sc1.z, sh1.z), 0.f);
        v1.w = fmaxf(fmaf(v1.w, sc1.w, sh1.w), 0.f);
        if (!ok) {
            v0 = make_float4(0.f, 0.f, 0.f, 0.f);
            v1 = make_float4(0.f, 0.f, 0.f, 0.f);
        }
    }
    float vv[8] = {v0.x, v0.y, v0.z, v0.w, v1.x, v1.y, v1.z, v1.w};
    bf16x8 hv, lv;
#pragma unroll
    for (int j = 0; j < 8; j++) {
        unsigned short hh = f2bf(vv[j]);
        hv[j] = (short)hh;
        lv[j] = (short)f2bf(vv[j] - bf2f(hh));
    }
    hv_out = hv;
    lv_out = lv;
}

// ---------------- split-bf16 MFMA GEMM, fp32 A with optional fused BN+ReLU ------
template <int ACC, int BN>
__global__ __launch_bounds__(256) void k_mfma(const float* __restrict__ A,
                                              const unsigned short* __restrict__ Fh,
                                              const unsigned short* __restrict__ Fl,
                                              const float* __restrict__ scale,
                                              const float* __restrict__ shift,
                                              float* __restrict__ C, int ldc) {
    int lane = threadIdx.x & 63;
    int wid = threadIdx.x >> 6;
    int r16 = lane & 15, kq = lane >> 4;
    size_t mrow0 = (size_t)blockIdx.x * 128 + wid * 32;
    int colOff = blockIdx.y * 128;
    int ntBase = blockIdx.y * 8;

    bf16x8 ah[2][4], al[2][4];
#pragma unroll
    for (int mt = 0; mt < 2; mt++) {
        size_t row = mrow0 + mt * 16 + r16;
        bool ok = row < N_NODES;
#pragma unroll
        for (int ks = 0; ks < 4; ks++)
            load_a_frag(A, row, ok, kq, ks, scale, shift, BN, ah[mt][ks], al[mt][ks]);
    }

    f32x4 acc[2][8];
#pragma unroll
    for (int mt = 0; mt < 2; mt++)
#pragma unroll
        for (int nt = 0; nt < 8; nt++) acc[mt][nt] = (f32x4){0.f, 0.f, 0.f, 0.f};

#pragma unroll
    for (int nt = 0; nt < 8; nt++) {
        const unsigned short* pbh = Fh + ((size_t)(ntBase + nt) * 4 * 64 + lane) * 8;
        const unsigned short* pbl = Fl + ((size_t)(ntBase + nt) * 4 * 64 + lane) * 8;
        bf16x8 bh[4], bl[4];
#pragma unroll
        for (int ks = 0; ks < 4; ks++) {
            bh[ks] = *reinterpret_cast<const bf16x8*>(pbh + ks * 512);
            bl[ks] = *reinterpret_cast<const bf16x8*>(pbl + ks * 512);
        }
#pragma unroll
        for (int mt = 0; mt < 2; mt++)
#pragma unroll
            for (int ks = 0; ks < 4; ks++) {
                acc[mt][nt] = __builtin_amdgcn_mfma_f32_16x16x32_bf16(ah[mt][ks], bl[ks],
                                                                     acc[mt][nt], 0, 0, 0);
                acc[mt][nt] = __builtin_amdgcn_mfma_f32_16x16x32_bf16(al[mt][ks], bh[ks],
                                                                     acc[mt][nt], 0, 0, 0);
                acc[mt][nt] = __builtin_amdgcn_mfma_f32_16x16x32_bf16(ah[mt][ks], bh[ks],
                                                                     acc[mt][nt], 0, 0, 0);
            }
    }

#pragma unroll
    for (int mt = 0; mt < 2; mt++)
#pragma unroll
        for (int nt = 0; nt < 8; nt++)
#pragma unroll
            for (int r = 0; r < 4; r++) {
                size_t row = mrow0 + mt * 16 + kq * 4 + r;
                float* cp = C + row * ldc + colOff + nt * 16 + r16;
                float v = acc[mt][nt][r];
                if (ACC) v += *cp;
                *cp = v;
            }
}

// ------ layer-3 encoder GEMM + encp partial + bias + ReLU + segment pool --------
// full = encp_partial + BN_3(Uf)@encW_3 + encB; enc = relu(full) (pads masked);
// psum[g] += sum over rows of graph g.
__global__ __launch_bounds__(256) void k_enc3_pool(
    const float* __restrict__ Uf, const float* __restrict__ encp,
    const unsigned short* __restrict__ Fh, const unsigned short* __restrict__ Fl,
    const float* __restrict__ scale, const float* __restrict__ shift,
    const float* __restrict__ encB, const int* __restrict__ batch,
    float* __restrict__ psum) {
    int lane = threadIdx.x & 63;
    int wid = threadIdx.x >> 6;
    int r16 = lane & 15, kq = lane >> 4;
    size_t brow0 = (size_t)blockIdx.x * 128;
    size_t mrow0 = brow0 + wid * 32;
    int colOff = blockIdx.y * 128;
    int ntBase = blockIdx.y * 8;

    __shared__ int batch_lds[128];
    if (threadIdx.x < 128) {
        size_t row = brow0 + threadIdx.x;
        batch_lds[threadIdx.x] = (row < N_NODES) ? batch[row] : -1;
    }
    __syncthreads();

    bf16x8 ah[2][4], al[2][4];
#pragma unroll
    for (int mt = 0; mt < 2; mt++) {
        size_t row = mrow0 + mt * 16 + r16;
        bool ok = row < N_NODES;
#pragma unroll
        for (int ks = 0; ks < 4; ks++)
            load_a_frag(Uf, row, ok, kq, ks, scale, shift, 1, ah[mt][ks], al[mt][ks]);
    }

    f32x4 acc[2][8];
#pragma unroll
    for (int mt = 0; mt < 2; mt++)
#pragma unroll
        for (int nt = 0; nt < 8; nt++) acc[mt][nt] = (f32x4){0.f, 0.f, 0.f, 0.f};

#pragma unroll
    for (int nt = 0; nt < 8; nt++) {
        const unsigned short* pbh = Fh + ((size_t)(ntBase + nt) * 4 * 64 + lane) * 8;
        const unsigned short* pbl = Fl + ((size_t)(ntBase + nt) * 4 * 64 + lane) * 8;
        bf16x8 bh[4], bl[4];
#pragma unroll
        for (int ks = 0; ks < 4; ks++) {
            bh[ks] = *reinterpret_cast<const bf16x8*>(pbh + ks * 512);
            bl[ks] = *reinterpret_cast<const bf16x8*>(pbl + ks * 512);
        }
#pragma unroll
        for (int mt = 0; mt < 2; mt++)
#pragma unroll
            for (int ks = 0; ks < 4; ks++) {
                acc[mt][nt] = __builtin_amdgcn_mfma_f32_16x16x32_bf16(ah[mt][ks], bl[ks],
                                                                     acc[mt][nt], 0, 0, 0);
                acc[mt][nt] = __builtin_amdgcn_mfma_f32_16x16x32_bf16(al[mt][ks], bh[ks],
                                                                     acc[mt][nt], 0, 0, 0);
                acc[mt][nt] = __builtin_amdgcn_mfma_f32_16x16x32_bf16(ah[mt][ks], bh[ks],
                                                                     acc[mt][nt], 0, 0, 0);
            }
    }

    // full = acc + encp partial + bias; relu; mask pads
    float bias[8];
#pragma unroll
    for (int nt = 0; nt < 8; nt++) bias[nt] = encB[colOff + nt * 16 + r16];
#pragma unroll
    for (int mt = 0; mt < 2; mt++)
#pragma unroll
        for (int r = 0; r < 4; r++) {
            size_t row = mrow0 + mt * 16 + kq * 4 + r;
            bool valid = batch_lds[wid * 32 + mt * 16 + kq * 4 + r] >= 0;
            const float* pp = encp + row * ENCDIM + colOff + r16;
#pragma unroll
            for (int nt = 0; nt < 8; nt++) {
                float v = acc[mt][nt][r] + pp[nt * 16] + bias[nt];
                acc[mt][nt][r] = valid ? fmaxf(v, 0.f) : 0.f;
            }
        }

    // segment pool: block spans few graphs (batch sorted)
    int lastIdx = (int)((N_NODES - 1 - brow0) < 127 ? (N_NODES - 1 - brow0) : 127);
    int g0 = batch_lds[0];
    int g1 = batch_lds[lastIdx];
    __shared__ float sred[4][128];
    for (int g = g0; g <= g1; ++g) {
        float s[8];
#pragma unroll
        for (int nt = 0; nt < 8; nt++) s[nt] = 0.f;
#pragma unroll
        for (int mt = 0; mt < 2; mt++)
#pragma unroll
            for (int r = 0; r < 4; r++) {
                bool m = batch_lds[wid * 32 + mt * 16 + kq * 4 + r] == g;
                if (m) {
#pragma unroll
                    for (int nt = 0; nt < 8; nt++) s[nt] += acc[mt][nt][r];
                }
            }
#pragma unroll
        for (int nt = 0; nt < 8; nt++) {
            s[nt] += __shfl_xor(s[nt], 16);
            s[nt] += __shfl_xor(s[nt], 32);
        }
        if (lane < 16) {
#pragma unroll
            for (int nt = 0; nt < 8; nt++) sred[wid][nt * 16 + r16] = s[nt];
        }
        __syncthreads();
        if (threadIdx.x < 128) {
            float tot = sred[0][threadIdx.x] + sred[1][threadIdx.x] +
                        sred[2][threadIdx.x] + sred[3][threadIdx.x];
            atomicAdd(&psum[(size_t)g * ENCDIM + colOff + threadIdx.x], tot);
        }
        __syncthreads();
    }
}

// ---------------- aggregation: Uf <- S * hw + bias (fp32 out) ----------------
__global__ __launch_bounds__(256) void k_agg(const float4* __restrict__ hw4,
                                             const int* __restrict__ rs,
                                             const int* __restrict__ cnt,
                                             const int2* __restrict__ csr_ew,
                                             const float* __restrict__ dinv,
                                             const float4* __restrict__ bias4,
                                             float4* __restrict__ Uf4) {
    int n = blockIdx.x * 8 + (threadIdx.x >> 5);
    int lane = threadIdx.x & 31;
    if (n >= N_NODES) return;
    float d = dinv[n];
    float dd = d * d;
    float4 self = hw4[(size_t)n * 32 + lane];
    float4 b = bias4[lane];
    float4 acc;
    acc.x = fmaf(dd, self.x, b.x);
    acc.y = fmaf(dd, self.y, b.y);
    acc.z = fmaf(dd, self.z, b.z);
    acc.w = fmaf(dd, self.w, b.w);
    int s0 = rs[n];
    int c = cnt[n];
    int e = 0;
    for (; e + 8 <= c; e += 8) {
        int2 ee[8];
        float4 vv[8];
#pragma unroll
        for (int u = 0; u < 8; u++) ee[u] = csr_ew[s0 + e + u];
#pragma unroll
        for (int u = 0; u < 8; u++) vv[u] = hw4[(size_t)ee[u].x * 32 + lane];
#pragma unroll
        for (int u = 0; u < 8; u++) {
            float w = __int_as_float(ee[u].y);
            acc.x = fmaf(w, vv[u].x, acc.x);
            acc.y = fmaf(w, vv[u].y, acc.y);
            acc.z = fmaf(w, vv[u].z, acc.z);
            acc.w = fmaf(w, vv[u].w, acc.w);
        }
    }
    for (; e < c; e++) {
        int2 ee = csr_ew[s0 + e];
        float4 v = hw4[(size_t)ee.x * 32 + lane];
        float w = __int_as_float(ee.y);
        acc.x = fmaf(w, v.x, acc.x); acc.y = fmaf(w, v.y, acc.y);
        acc.z = fmaf(w, v.z, acc.z); acc.w = fmaf(w, v.w, acc.w);
    }
    Uf4[(size_t)n * 32 + lane] = acc;
}

// ---------------- BN stats on fp32 Uf ----------------
__global__ __launch_bounds__(256) void k_bn_stats(const float4* __restrict__ Uf4,
                                                  float* __restrict__ sum,
                                                  float* __restrict__ sq) {
    int c4 = threadIdx.x & 31;  // float4 column = features 4*c4..4*c4+3
    int y = threadIdx.x >> 5;   // 8 row-groups
    float4 s = make_float4(0.f, 0.f, 0.f, 0.f);
    float4 q = make_float4(0.f, 0.f, 0.f, 0.f);
    for (size_t n = (size_t)blockIdx.x * 8 + y; n < N_NODES; n += (size_t)gridDim.x * 8) {
        float4 v = Uf4[n * 32 + c4];
        s.x += v.x; s.y += v.y; s.z += v.z; s.w += v.w;
        q.x = fmaf(v.x, v.x, q.x); q.y = fmaf(v.y, v.y, q.y);
        q.z = fmaf(v.z, v.z, q.z); q.w = fmaf(v.w, v.w, q.w);
    }
    __shared__ float4 ls[256], lq[256];
    ls[threadIdx.x] = s;
    lq[threadIdx.x] = q;
    __syncthreads();
    if (y == 0) {
#pragma unroll
        for (int yy = 1; yy < 8; yy++) {
            float4 a = ls[yy * 32 + c4], b = lq[yy * 32 + c4];
            s.x += a.x; s.y += a.y; s.z += a.z; s.w += a.w;
            q.x += b.x; q.y += b.y; q.z += b.z; q.w += b.w;
        }
        atomicAdd(&sum[c4 * 4 + 0], s.x);
        atomicAdd(&sum[c4 * 4 + 1], s.y);
        atomicAdd(&sum[c4 * 4 + 2], s.z);
        atomicAdd(&sum[c4 * 4 + 3], s.w);
        atomicAdd(&sq[c4 * 4 + 0], q.x);
        atomicAdd(&sq[c4 * 4 + 1], q.y);
        atomicAdd(&sq[c4 * 4 + 2], q.z);
        atomicAdd(&sq[c4 * 4 + 3], q.w);
    }
}

__global__ void k_bn_finalize(const float* __restrict__ sum, const float* __restrict__ sq,
                              const float* __restrict__ gamma, const float* __restrict__ beta,
                              float* __restrict__ scale, float* __restrict__ shift) {
    int f = threadIdx.x;
    float mu = sum[f] * (1.0f / N_NODES);
    float var = sq[f] * (1.0f / N_NODES) - mu * mu;
    float s = rsqrtf(var + EPS_BN) * gamma[f];
    scale[f] = s;
    shift[f] = beta[f] - mu * s;
}

// ---------------- pool finalize + decoder ----------------
__global__ void k_pool_fin(const float* __restrict__ psum, const int* __restrict__ gcnt,
                           float* __restrict__ pooled) {
    int i = blockIdx.x * 256 + threadIdx.x;  // 65536
    int g = i >> 8;
    pooled[i] = psum[i] / fmaxf((float)gcnt[g], 1.0f);
}

__global__ __launch_bounds__(128) void k_dec(const float* __restrict__ pooled,
                                             const float* __restrict__ W1,
                                             const float* __restrict__ b1,
                                             const float* __restrict__ W2,
                                             const float* __restrict__ b2,
                                             float* __restrict__ out) {
    int g = blockIdx.x;
    int j = threadIdx.x;
    const float* p = &pooled[g * ENCDIM];
    float acc = b1[j];
    for (int k = 0; k < ENCDIM; k++) acc = fmaf(p[k], W1[k * 128 + j], acc);
    float h = fmaxf(acc, 0.f) * W2[j];
    for (int off = 32; off; off >>= 1) h += __shfl_down(h, off);
    __shared__ float red[2];
    if ((j & 63) == 0) red[j >> 6] = h;
    __syncthreads();
    if (j == 0) out[g] = red[0] + red[1] + b2[0];
}

extern "C" void kernel_launch(void* const* d_in, const int* in_sizes, int n_in,
                              void* d_out, int out_size, void* d_ws, size_t ws_size,
                              hipStream_t stream) {
    const float* x = (const float*)d_in[0];
    const int* ei = (const int*)d_in[1];
    const int* src = ei;
    const int* dst = ei + N_EDGES;
    const int* batch = (const int*)d_in[2];
    const float* convW = (const float*)d_in[3];
    const float* convB = (const float*)d_in[4];
    const float* gamma = (const float*)d_in[5];
    const float* beta = (const float*)d_in[6];
    const float* encW = (const float*)d_in[7];
    const float* encB = (const float*)d_in[8];
    const float* dW1 = (const float*)d_in[9];
    const float* db1 = (const float*)d_in[10];
    const float* dW2 = (const float*)d_in[11];
    const float* db2 = (const float*)d_in[12];
    float* out = (float*)d_out;

    char* w = (char*)d_ws;
    auto alloc = [&](size_t bytes) {
        char* p = w;
        w += (bytes + 255) & ~(size_t)255;
        return p;
    };
    // workspace budget: ~221 MB (within proven R5/R6 envelope; R7's 272 MB crashed)
    int* cnt = (int*)alloc((size_t)N_NODES * 4);
    int* rs = (int*)alloc((size_t)N_NODES * 4);
    int* cursor = (int*)alloc((size_t)N_NODES * 4);
    int* bsums = (int*)alloc(512 * 4);
    float* dinv = (float*)alloc((size_t)N_NODES * 4);
    int2* csr_ew = (int2*)alloc((size_t)N_EDGES * 8);
    float* Uf = (float*)alloc((size_t)N_NODES * HDIM * 4);      // raw agg out (fp32)
    float* B = (float*)alloc((size_t)NPAD * HDIM * 4);          // hw fp32
    float* encp = (float*)alloc((size_t)NPAD * ENCDIM * 4);     // encoder partial (l0-2)
    unsigned short* convWfh = (unsigned short*)alloc((size_t)NLAYERS * 16384 * 2);
    unsigned short* convWfl = (unsigned short*)alloc((size_t)NLAYERS * 16384 * 2);
    unsigned short* encWfh = (unsigned short*)alloc((size_t)NLAYERS * 32768 * 2);
    unsigned short* encWfl = (unsigned short*)alloc((size_t)NLAYERS * 32768 * 2);
    float* bnsum = (float*)alloc(128 * 4);
    float* bnsq = (float*)alloc(128 * 4);
    float* bnscale = (float*)alloc(128 * 4);
    float* bnshift = (float*)alloc(128 * 4);
    int* gcnt = (int*)alloc(256 * 4);
    int* gstart = (int*)alloc(256 * 4);
    float* psum = (float*)alloc(256 * 256 * 4);
    float* pooled = (float*)alloc(256 * 256 * 4);

    // CSR build + degree normalization
    hipMemsetAsync(cnt, 0, (size_t)N_NODES * 4, stream);
    k_count<<<(N_EDGES + 255) / 256, 256, 0, stream>>>(dst, cnt);
    k_dinv<<<(N_NODES + 255) / 256, 256, 0, stream>>>(cnt, dinv);
    int nb = (N_NODES + 255) / 256;  // 391
    k_scan_block<<<nb, 256, 0, stream>>>(cnt, rs, bsums);
    k_scan_sums<<<1, 512, 0, stream>>>(bsums, nb);
    k_scan_add<<<nb, 256, 0, stream>>>(rs, bsums, cursor);
    k_scatter<<<(N_EDGES + 255) / 256, 256, 0, stream>>>(src, dst, dinv, cursor, csr_ew);
    k_gbounds<<<1, 256, 0, stream>>>(batch, gstart, gcnt);

    // weight fragment permute + split (tiny)
    for (int l = 0; l < NLAYERS; l++) {
        k_wfrag<<<8, 256, 0, stream>>>(convW + (size_t)l * 16384, 128, 8,
                                       convWfh + (size_t)l * 16384,
                                       convWfl + (size_t)l * 16384);
        k_wfrag<<<16, 256, 0, stream>>>(encW + (size_t)l * 128 * 256, 256, 16,
                                        encWfh + (size_t)l * 32768,
                                        encWfl + (size_t)l * 32768);
    }

    for (int l = 0; l < NLAYERS; l++) {
        // hw = h @ convW_l  (h = x for l=0, else BN_{l-1}(Uf) fused in-register)
        if (l == 0)
            k_mfma<0, 0><<<dim3(NPAD / 128, 1), 256, 0, stream>>>(
                x, convWfh + (size_t)l * 16384, convWfl + (size_t)l * 16384,
                nullptr, nullptr, B, 128);
        else
            k_mfma<0, 1><<<dim3(NPAD / 128, 1), 256, 0, stream>>>(
                Uf, convWfh + (size_t)l * 16384, convWfl + (size_t)l * 16384,
                bnscale, bnshift, B, 128);
        // aggregate + bias -> Uf (raw, fp32)
        k_agg<<<N_NODES / 8, 256, 0, stream>>>((const float4*)B, rs, cnt, csr_ew, dinv,
                                               (const float4*)(convB + l * 128),
                                               (float4*)Uf);
        // BN stats
        hipMemsetAsync(bnsum, 0, 128 * 4, stream);
        hipMemsetAsync(bnsq, 0, 128 * 4, stream);
        k_bn_stats<<<512, 256, 0, stream>>>((const float4*)Uf, bnsum, bnsq);
        k_bn_finalize<<<1, 128, 0, stream>>>(bnsum, bnsq, gamma + l * 128, beta + l * 128,
                                             bnscale, bnshift);
        // encoder partial for l=0..2: encp (+)= BN_l(Uf) @ encW_l
        if (l == 0)
            k_mfma<0, 1><<<dim3(NPAD / 128, 2), 256, 0, stream>>>(
                Uf, encWfh + (size_t)l * 32768, encWfl + (size_t)l * 32768,
                bnscale, bnshift, encp, 256);
        else if (l < 3)
            k_mfma<1, 1><<<dim3(NPAD / 128, 2), 256, 0, stream>>>(
                Uf, encWfh + (size_t)l * 32768, encWfl + (size_t)l * 32768,
                bnscale, bnshift, encp, 256);
    }

    // layer-3 encoder GEMM + encp partial + bias + ReLU + segment pool (fused)
    hipMemsetAsync(psum, 0, 256 * 256 * 4, stream);
    k_enc3_pool<<<dim3(NPAD / 128, 2), 256, 0, stream>>>(
        Uf, encp, encWfh + (size_t)3 * 32768, encWfl + (size_t)3 * 32768,
        bnscale, bnshift, encB, batch, psum);
    k_pool_fin<<<256, 256, 0, stream>>>(psum, gcnt, pooled);
    k_dec<<<256, 128, 0, stream>>>(pooled, dW1, db1, dW2, db2, out);
}

// Round 9
// 1287.835 us; speedup vs baseline: 8.1956x; 1.0992x over previous
//
#include <hip/hip_runtime.h>
#include <hip/hip_bf16.h>

#define N_NODES 100000
#define NPAD    100096   // 782 * 128
#define N_EDGES 1600000
#define HDIM 128
#define NLAYERS 4
#define NGRAPH 256
#define ENCDIM 256
#define EPS_BN 1e-5f

typedef __attribute__((ext_vector_type(8))) short bf16x8;
typedef __attribute__((ext_vector_type(4))) float f32x4;

__device__ __forceinline__ unsigned short f2bf(float v) {
    unsigned int u = __float_as_uint(v);
    u += 0x7FFFu + ((u >> 16) & 1u);
    return (unsigned short)(u >> 16);
}
__device__ __forceinline__ float bf2f(unsigned int lo16) {
    return __uint_as_float(lo16 << 16);
}

// ---------------- CSR build ----------------
__global__ void k_count(const int* __restrict__ dst, int* __restrict__ cnt) {
    int e = blockIdx.x * 256 + threadIdx.x;
    if (e < N_EDGES) atomicAdd(&cnt[dst[e]], 1);
}

__global__ void k_dinv(const int* __restrict__ cnt, float* __restrict__ dinv) {
    int n = blockIdx.x * 256 + threadIdx.x;
    if (n < N_NODES) dinv[n] = rsqrtf((float)cnt[n] + 1.0f);
}

__global__ void k_scan_block(const int* __restrict__ cnt, int* __restrict__ excl,
                             int* __restrict__ bsums) {
    __shared__ int s[256];
    int t = threadIdx.x;
    int i = blockIdx.x * 256 + t;
    int v = (i < N_NODES) ? cnt[i] : 0;
    s[t] = v;
    __syncthreads();
    for (int off = 1; off < 256; off <<= 1) {
        int x = 0;
        if (t >= off) x = s[t - off];
        __syncthreads();
        if (t >= off) s[t] += x;
        __syncthreads();
    }
    if (i < N_NODES) excl[i] = s[t] - v;
    if (t == 255) bsums[blockIdx.x] = s[255];
}

__global__ void k_scan_sums(int* __restrict__ bsums, int nb) {
    __shared__ int s[512];
    int t = threadIdx.x;
    int v = (t < nb) ? bsums[t] : 0;
    s[t] = v;
    __syncthreads();
    for (int off = 1; off < 512; off <<= 1) {
        int x = 0;
        if (t >= off) x = s[t - off];
        __syncthreads();
        if (t >= off) s[t] += x;
        __syncthreads();
    }
    if (t < nb) bsums[t] = s[t] - v;
}

__global__ void k_scan_add(int* __restrict__ excl, const int* __restrict__ bsums,
                           int* __restrict__ cursor) {
    int i = blockIdx.x * 256 + threadIdx.x;
    if (i < N_NODES) {
        int v = excl[i] + bsums[blockIdx.x];
        excl[i] = v;
        cursor[i] = v;
    }
}

__global__ void k_scatter(const int* __restrict__ src, const int* __restrict__ dst,
                          const float* __restrict__ dinv, int* __restrict__ cursor,
                          int2* __restrict__ csr_ew) {
    int e = blockIdx.x * 256 + threadIdx.x;
    if (e < N_EDGES) {
        int d = dst[e];
        int s = src[e];
        int p = atomicAdd(&cursor[d], 1);
        int2 v;
        v.x = s;
        v.y = __float_as_int(dinv[s] * dinv[d]);
        csr_ew[p] = v;
    }
}

// ---------------- graph bounds via binary search (batch is sorted) ----------------
__global__ void k_gbounds(const int* __restrict__ batch, int* __restrict__ gstart,
                          int* __restrict__ gcnt) {
    __shared__ int s[257];
    int g = threadIdx.x;  // 256 threads
    int lo = 0, hi = N_NODES;
    while (lo < hi) {
        int mid = (lo + hi) >> 1;
        if (batch[mid] < g) lo = mid + 1; else hi = mid;
    }
    s[g] = lo;
    if (g == 255) s[256] = N_NODES;
    __syncthreads();
    gstart[g] = s[g];
    gcnt[g] = s[g + 1] - s[g];
}

// ---------------- weight -> MFMA B-fragment order, split hi/lo ----------------
// F[((nt*4 + ks)*64 + lane)*8 + j] = W[(ks*32 + (lane>>4)*8 + j)*ldw + nt*16 + (lane&15)]
__global__ void k_wfrag(const float* __restrict__ W, int ldw, int ntiles,
                        unsigned short* __restrict__ Fh, unsigned short* __restrict__ Fl) {
    int t = blockIdx.x * 256 + threadIdx.x;
    if (t >= ntiles * 256) return;
    int lane = t & 63, ks = (t >> 6) & 3, nt = t >> 8;
    int r16 = lane & 15, kq = lane >> 4;
    unsigned short h[8], l[8];
#pragma unroll
    for (int j = 0; j < 8; j++) {
        float w = W[(size_t)(ks * 32 + kq * 8 + j) * ldw + nt * 16 + r16];
        unsigned short hh = f2bf(w);
        h[j] = hh;
        l[j] = f2bf(w - bf2f(hh));
    }
    ((ushort4*)(Fh + (size_t)t * 8))[0] = make_ushort4(h[0], h[1], h[2], h[3]);
    ((ushort4*)(Fh + (size_t)t * 8))[1] = make_ushort4(h[4], h[5], h[6], h[7]);
    ((ushort4*)(Fl + (size_t)t * 8))[0] = make_ushort4(l[0], l[1], l[2], l[3]);
    ((ushort4*)(Fl + (size_t)t * 8))[1] = make_ushort4(l[4], l[5], l[6], l[7]);
}

// ---------------- helper: load fp32 A + optional BN+ReLU + hi/lo split ----------
__device__ __forceinline__ void load_a_frag(const float* __restrict__ A, size_t row,
                                            bool ok, int kq, int ks,
                                            const float* __restrict__ scale,
                                            const float* __restrict__ shift, int useBN,
                                            bf16x8& hv_out, bf16x8& lv_out) {
    float4 v0 = make_float4(0.f, 0.f, 0.f, 0.f);
    float4 v1 = make_float4(0.f, 0.f, 0.f, 0.f);
    if (ok) {
        const float* pa = A + row * 128 + kq * 8 + ks * 32;
        v0 = *(const float4*)pa;
        v1 = *(const float4*)(pa + 4);
    }
    if (useBN) {
        int f0 = ks * 32 + kq * 8;
        float4 sc0 = *(const float4*)&scale[f0];
        float4 sc1 = *(const float4*)&scale[f0 + 4];
        float4 sh0 = *(const float4*)&shift[f0];
        float4 sh1 = *(const float4*)&shift[f0 + 4];
        v0.x = fmaxf(fmaf(v0.x, sc0.x, sh0.x), 0.f);
        v0.y = fmaxf(fmaf(v0.y, sc0.y, sh0.y), 0.f);
        v0.z = fmaxf(fmaf(v0.z, sc0.z, sh0.z), 0.f);
        v0.w = fmaxf(fmaf(v0.w, sc0.w, sh0.w), 0.f);
        v1.x = fmaxf(fmaf(v1.x, sc1.x, sh1.x), 0.f);
        v1.y = fmaxf(fmaf(v1.y, sc1.y, sh1.y), 0.f);
        v1.z = fmaxf(fmaf(v1.z, sc1.z, sh1.z), 0.f);
        v1.w = fmaxf(fmaf(v1.w, sc1.w, sh1.w), 0.f);
        if (!ok) {
            v0 = make_float4(0.f, 0.f, 0.f, 0.f);
            v1 = make_float4(0.f, 0.f, 0.f, 0.f);
        }
    }
    float vv[8] = {v0.x, v0.y, v0.z, v0.w, v1.x, v1.y, v1.z, v1.w};
    bf16x8 hv, lv;
#pragma unroll
    for (int j = 0; j < 8; j++) {
        unsigned short hh = f2bf(vv[j]);
        hv[j] = (short)hh;
        lv[j] = (short)f2bf(vv[j] - bf2f(hh));
    }
    hv_out = hv;
    lv_out = lv;
}

// ---- helper: load raw-bf16 A, BN+ReLU in fp32, hi/lo split (encoder path) ------
__device__ __forceinline__ void load_a_frag_bf(const unsigned short* __restrict__ Ub,
                                               size_t row, bool ok, int kq, int ks,
                                               const float* __restrict__ scale,
                                               const float* __restrict__ shift,
                                               bf16x8& hv_out, bf16x8& lv_out) {
    float vv[8];
    if (ok) {
        bf16x8 raw = *reinterpret_cast<const bf16x8*>(Ub + row * 128 + ks * 32 + kq * 8);
#pragma unroll
        for (int j = 0; j < 8; j++) vv[j] = bf2f((unsigned short)raw[j]);
    } else {
#pragma unroll
        for (int j = 0; j < 8; j++) vv[j] = 0.f;
    }
    int f0 = ks * 32 + kq * 8;
    float4 sc0 = *(const float4*)&scale[f0];
    float4 sc1 = *(const float4*)&scale[f0 + 4];
    float4 sh0 = *(const float4*)&shift[f0];
    float4 sh1 = *(const float4*)&shift[f0 + 4];
    float scv[8] = {sc0.x, sc0.y, sc0.z, sc0.w, sc1.x, sc1.y, sc1.z, sc1.w};
    float shv[8] = {sh0.x, sh0.y, sh0.z, sh0.w, sh1.x, sh1.y, sh1.z, sh1.w};
    bf16x8 hv, lv;
#pragma unroll
    for (int j = 0; j < 8; j++) {
        float v = ok ? fmaxf(fmaf(vv[j], scv[j], shv[j]), 0.f) : 0.f;
        unsigned short hh = f2bf(v);
        hv[j] = (short)hh;
        lv[j] = (short)f2bf(v - bf2f(hh));
    }
    hv_out = hv;
    lv_out = lv;
}

// ---------------- split-bf16 MFMA GEMM, fp32 A with optional fused BN+ReLU ------
template <int ACC, int BN>
__global__ __launch_bounds__(256) void k_mfma(const float* __restrict__ A,
                                              const unsigned short* __restrict__ Fh,
                                              const unsigned short* __restrict__ Fl,
                                              const float* __restrict__ scale,
                                              const float* __restrict__ shift,
                                              float* __restrict__ C, int ldc) {
    int lane = threadIdx.x & 63;
    int wid = threadIdx.x >> 6;
    int r16 = lane & 15, kq = lane >> 4;
    size_t mrow0 = (size_t)blockIdx.x * 128 + wid * 32;
    int colOff = blockIdx.y * 128;
    int ntBase = blockIdx.y * 8;

    bf16x8 ah[2][4], al[2][4];
#pragma unroll
    for (int mt = 0; mt < 2; mt++) {
        size_t row = mrow0 + mt * 16 + r16;
        bool ok = row < N_NODES;
#pragma unroll
        for (int ks = 0; ks < 4; ks++)
            load_a_frag(A, row, ok, kq, ks, scale, shift, BN, ah[mt][ks], al[mt][ks]);
    }

    f32x4 acc[2][8];
#pragma unroll
    for (int mt = 0; mt < 2; mt++)
#pragma unroll
        for (int nt = 0; nt < 8; nt++) acc[mt][nt] = (f32x4){0.f, 0.f, 0.f, 0.f};

#pragma unroll
    for (int nt = 0; nt < 8; nt++) {
        const unsigned short* pbh = Fh + ((size_t)(ntBase + nt) * 4 * 64 + lane) * 8;
        const unsigned short* pbl = Fl + ((size_t)(ntBase + nt) * 4 * 64 + lane) * 8;
        bf16x8 bh[4], bl[4];
#pragma unroll
        for (int ks = 0; ks < 4; ks++) {
            bh[ks] = *reinterpret_cast<const bf16x8*>(pbh + ks * 512);
            bl[ks] = *reinterpret_cast<const bf16x8*>(pbl + ks * 512);
        }
#pragma unroll
        for (int mt = 0; mt < 2; mt++)
#pragma unroll
            for (int ks = 0; ks < 4; ks++) {
                acc[mt][nt] = __builtin_amdgcn_mfma_f32_16x16x32_bf16(ah[mt][ks], bl[ks],
                                                                     acc[mt][nt], 0, 0, 0);
                acc[mt][nt] = __builtin_amdgcn_mfma_f32_16x16x32_bf16(al[mt][ks], bh[ks],
                                                                     acc[mt][nt], 0, 0, 0);
                acc[mt][nt] = __builtin_amdgcn_mfma_f32_16x16x32_bf16(ah[mt][ks], bh[ks],
                                                                     acc[mt][nt], 0, 0, 0);
            }
    }

#pragma unroll
    for (int mt = 0; mt < 2; mt++)
#pragma unroll
        for (int nt = 0; nt < 8; nt++)
#pragma unroll
            for (int r = 0; r < 4; r++) {
                size_t row = mrow0 + mt * 16 + kq * 4 + r;
                float* cp = C + row * ldc + colOff + nt * 16 + r16;
                float v = acc[mt][nt][r];
                if (ACC) v += *cp;
                *cp = v;
            }
}

// ------ fused K=512 encoder GEMM (bf16 layer inputs) + bias + ReLU + pool --------
__global__ __launch_bounds__(256) void k_enc_pool(
    const unsigned short* __restrict__ Ub0, const unsigned short* __restrict__ Ub1,
    const unsigned short* __restrict__ Ub2, const unsigned short* __restrict__ Ub3,
    const unsigned short* __restrict__ Fh, const unsigned short* __restrict__ Fl,
    const float* __restrict__ scaleAll, const float* __restrict__ shiftAll,
    const float* __restrict__ encB, const int* __restrict__ batch,
    float* __restrict__ psum) {
    int lane = threadIdx.x & 63;
    int wid = threadIdx.x >> 6;
    int r16 = lane & 15, kq = lane >> 4;
    size_t brow0 = (size_t)blockIdx.x * 128;
    size_t mrow0 = brow0 + wid * 32;
    int colOff = blockIdx.y * 128;
    int ntBase = blockIdx.y * 8;

    __shared__ int batch_lds[128];
    if (threadIdx.x < 128) {
        size_t row = brow0 + threadIdx.x;
        batch_lds[threadIdx.x] = (row < N_NODES) ? batch[row] : -1;
    }
    __syncthreads();

    f32x4 acc[2][8];
#pragma unroll
    for (int mt = 0; mt < 2; mt++)
#pragma unroll
        for (int nt = 0; nt < 8; nt++) acc[mt][nt] = (f32x4){0.f, 0.f, 0.f, 0.f};

    const unsigned short* Ubs[4] = {Ub0, Ub1, Ub2, Ub3};
#pragma unroll
    for (int l = 0; l < 4; l++) {
        const unsigned short* Ub = Ubs[l];
        const float* scale = scaleAll + l * 128;
        const float* shift = shiftAll + l * 128;
        bf16x8 ah[2][4], al[2][4];
#pragma unroll
        for (int mt = 0; mt < 2; mt++) {
            size_t row = mrow0 + mt * 16 + r16;
            bool ok = row < N_NODES;
#pragma unroll
            for (int ks = 0; ks < 4; ks++)
                load_a_frag_bf(Ub, row, ok, kq, ks, scale, shift, ah[mt][ks], al[mt][ks]);
        }
        const unsigned short* Fhl = Fh + (size_t)l * 32768;
        const unsigned short* Fll = Fl + (size_t)l * 32768;
#pragma unroll
        for (int nt = 0; nt < 8; nt++) {
            const unsigned short* pbh = Fhl + ((size_t)(ntBase + nt) * 4 * 64 + lane) * 8;
            const unsigned short* pbl = Fll + ((size_t)(ntBase + nt) * 4 * 64 + lane) * 8;
            bf16x8 bh[4], bl[4];
#pragma unroll
            for (int ks = 0; ks < 4; ks++) {
                bh[ks] = *reinterpret_cast<const bf16x8*>(pbh + ks * 512);
                bl[ks] = *reinterpret_cast<const bf16x8*>(pbl + ks * 512);
            }
#pragma unroll
            for (int mt = 0; mt < 2; mt++)
#pragma unroll
                for (int ks = 0; ks < 4; ks++) {
                    acc[mt][nt] = __builtin_amdgcn_mfma_f32_16x16x32_bf16(
                        ah[mt][ks], bl[ks], acc[mt][nt], 0, 0, 0);
                    acc[mt][nt] = __builtin_amdgcn_mfma_f32_16x16x32_bf16(
                        al[mt][ks], bh[ks], acc[mt][nt], 0, 0, 0);
                    acc[mt][nt] = __builtin_amdgcn_mfma_f32_16x16x32_bf16(
                        ah[mt][ks], bh[ks], acc[mt][nt], 0, 0, 0);
                }
        }
    }

    // relu(acc + encB), pads zeroed
    float bias[8];
#pragma unroll
    for (int nt = 0; nt < 8; nt++) bias[nt] = encB[colOff + nt * 16 + r16];
#pragma unroll
    for (int mt = 0; mt < 2; mt++)
#pragma unroll
        for (int r = 0; r < 4; r++) {
            bool valid = batch_lds[wid * 32 + mt * 16 + kq * 4 + r] >= 0;
#pragma unroll
            for (int nt = 0; nt < 8; nt++)
                acc[mt][nt][r] = valid ? fmaxf(acc[mt][nt][r] + bias[nt], 0.f) : 0.f;
        }

    // segment pool (batch sorted; block spans few graphs)
    int lastIdx = (int)((N_NODES - 1 - brow0) < 127 ? (N_NODES - 1 - brow0) : 127);
    int g0 = batch_lds[0];
    int g1 = batch_lds[lastIdx];
    __shared__ float sred[4][128];
    for (int g = g0; g <= g1; ++g) {
        float s[8];
#pragma unroll
        for (int nt = 0; nt < 8; nt++) s[nt] = 0.f;
#pragma unroll
        for (int mt = 0; mt < 2; mt++)
#pragma unroll
            for (int r = 0; r < 4; r++) {
                bool m = batch_lds[wid * 32 + mt * 16 + kq * 4 + r] == g;
                if (m) {
#pragma unroll
                    for (int nt = 0; nt < 8; nt++) s[nt] += acc[mt][nt][r];
                }
            }
#pragma unroll
        for (int nt = 0; nt < 8; nt++) {
            s[nt] += __shfl_xor(s[nt], 16);
            s[nt] += __shfl_xor(s[nt], 32);
        }
        if (lane < 16) {
#pragma unroll
            for (int nt = 0; nt < 8; nt++) sred[wid][nt * 16 + r16] = s[nt];
        }
        __syncthreads();
        if (threadIdx.x < 128) {
            float tot = sred[0][threadIdx.x] + sred[1][threadIdx.x] +
                        sred[2][threadIdx.x] + sred[3][threadIdx.x];
            atomicAdd(&psum[(size_t)g * ENCDIM + colOff + threadIdx.x], tot);
        }
        __syncthreads();
    }
}

// ------ aggregation: Uf(fp32) + Ub(raw bf16) <- S * hw + bias --------------------
__global__ __launch_bounds__(256) void k_agg(const float4* __restrict__ hw4,
                                             const int* __restrict__ rs,
                                             const int* __restrict__ cnt,
                                             const int2* __restrict__ csr_ew,
                                             const float* __restrict__ dinv,
                                             const float4* __restrict__ bias4,
                                             float4* __restrict__ Uf4,
                                             unsigned short* __restrict__ Ub) {
    int n = blockIdx.x * 8 + (threadIdx.x >> 5);
    int lane = threadIdx.x & 31;
    if (n >= N_NODES) return;
    float d = dinv[n];
    float dd = d * d;
    float4 self = hw4[(size_t)n * 32 + lane];
    float4 b = bias4[lane];
    float4 acc;
    acc.x = fmaf(dd, self.x, b.x);
    acc.y = fmaf(dd, self.y, b.y);
    acc.z = fmaf(dd, self.z, b.z);
    acc.w = fmaf(dd, self.w, b.w);
    int s0 = rs[n];
    int c = cnt[n];
    int e = 0;
    for (; e + 8 <= c; e += 8) {
        int2 ee[8];
        float4 vv[8];
#pragma unroll
        for (int u = 0; u < 8; u++) ee[u] = csr_ew[s0 + e + u];
#pragma unroll
        for (int u = 0; u < 8; u++) vv[u] = hw4[(size_t)ee[u].x * 32 + lane];
#pragma unroll
        for (int u = 0; u < 8; u++) {
            float w = __int_as_float(ee[u].y);
            acc.x = fmaf(w, vv[u].x, acc.x);
            acc.y = fmaf(w, vv[u].y, acc.y);
            acc.z = fmaf(w, vv[u].z, acc.z);
            acc.w = fmaf(w, vv[u].w, acc.w);
        }
    }
    for (; e < c; e++) {
        int2 ee = csr_ew[s0 + e];
        float4 v = hw4[(size_t)ee.x * 32 + lane];
        float w = __int_as_float(ee.y);
        acc.x = fmaf(w, v.x, acc.x); acc.y = fmaf(w, v.y, acc.y);
        acc.z = fmaf(w, v.z, acc.z); acc.w = fmaf(w, v.w, acc.w);
    }
    Uf4[(size_t)n * 32 + lane] = acc;
    ushort4 bv;
    bv.x = f2bf(acc.x);
    bv.y = f2bf(acc.y);
    bv.z = f2bf(acc.z);
    bv.w = f2bf(acc.w);
    *(ushort4*)(Ub + (size_t)n * 128 + lane * 4) = bv;
}

// ---------------- BN stats on fp32 Uf ----------------
__global__ __launch_bounds__(256) void k_bn_stats(const float4* __restrict__ Uf4,
                                                  float* __restrict__ sum,
                                                  float* __restrict__ sq) {
    int c4 = threadIdx.x & 31;  // float4 column = features 4*c4..4*c4+3
    int y = threadIdx.x >> 5;   // 8 row-groups
    float4 s = make_float4(0.f, 0.f, 0.f, 0.f);
    float4 q = make_float4(0.f, 0.f, 0.f, 0.f);
    for (size_t n = (size_t)blockIdx.x * 8 + y; n < N_NODES; n += (size_t)gridDim.x * 8) {
        float4 v = Uf4[n * 32 + c4];
        s.x += v.x; s.y += v.y; s.z += v.z; s.w += v.w;
        q.x = fmaf(v.x, v.x, q.x); q.y = fmaf(v.y, v.y, q.y);
        q.z = fmaf(v.z, v.z, q.z); q.w = fmaf(v.w, v.w, q.w);
    }
    __shared__ float4 ls[256], lq[256];
    ls[threadIdx.x] = s;
    lq[threadIdx.x] = q;
    __syncthreads();
    if (y == 0) {
#pragma unroll
        for (int yy = 1; yy < 8; yy++) {
            float4 a = ls[yy * 32 + c4], b = lq[yy * 32 + c4];
            s.x += a.x; s.y += a.y; s.z += a.z; s.w += a.w;
            q.x += b.x; q.y += b.y; q.z += b.z; q.w += b.w;
        }
        atomicAdd(&sum[c4 * 4 + 0], s.x);
        atomicAdd(&sum[c4 * 4 + 1], s.y);
        atomicAdd(&sum[c4 * 4 + 2], s.z);
        atomicAdd(&sum[c4 * 4 + 3], s.w);
        atomicAdd(&sq[c4 * 4 + 0], q.x);
        atomicAdd(&sq[c4 * 4 + 1], q.y);
        atomicAdd(&sq[c4 * 4 + 2], q.z);
        atomicAdd(&sq[c4 * 4 + 3], q.w);
    }
}

__global__ void k_bn_finalize(const float* __restrict__ sum, const float* __restrict__ sq,
                              const float* __restrict__ gamma, const float* __restrict__ beta,
                              float* __restrict__ scale, float* __restrict__ shift) {
    int f = threadIdx.x;
    float mu = sum[f] * (1.0f / N_NODES);
    float var = sq[f] * (1.0f / N_NODES) - mu * mu;
    float s = rsqrtf(var + EPS_BN) * gamma[f];
    scale[f] = s;
    shift[f] = beta[f] - mu * s;
}

// ---------------- pool finalize + decoder ----------------
__global__ void k_pool_fin(const float* __restrict__ psum, const int* __restrict__ gcnt,
                           float* __restrict__ pooled) {
    int i = blockIdx.x * 256 + threadIdx.x;  // 65536
    int g = i >> 8;
    pooled[i] = psum[i] / fmaxf((float)gcnt[g], 1.0f);
}

__global__ __launch_bounds__(128) void k_dec(const float* __restrict__ pooled,
                                             const float* __restrict__ W1,
                                             const float* __restrict__ b1,
                                             const float* __restrict__ W2,
                                             const float* __restrict__ b2,
                                             float* __restrict__ out) {
    int g = blockIdx.x;
    int j = threadIdx.x;
    const float* p = &pooled[g * ENCDIM];
    float acc = b1[j];
    for (int k = 0; k < ENCDIM; k++) acc = fmaf(p[k], W1[k * 128 + j], acc);
    float h = fmaxf(acc, 0.f) * W2[j];
    for (int off = 32; off; off >>= 1) h += __shfl_down(h, off);
    __shared__ float red[2];
    if ((j & 63) == 0) red[j >> 6] = h;
    __syncthreads();
    if (j == 0) out[g] = red[0] + red[1] + b2[0];
}

extern "C" void kernel_launch(void* const* d_in, const int* in_sizes, int n_in,
                              void* d_out, int out_size, void* d_ws, size_t ws_size,
                              hipStream_t stream) {
    const float* x = (const float*)d_in[0];
    const int* ei = (const int*)d_in[1];
    const int* src = ei;
    const int* dst = ei + N_EDGES;
    const int* batch = (const int*)d_in[2];
    const float* convW = (const float*)d_in[3];
    const float* convB = (const float*)d_in[4];
    const float* gamma = (const float*)d_in[5];
    const float* beta = (const float*)d_in[6];
    const float* encW = (const float*)d_in[7];
    const float* encB = (const float*)d_in[8];
    const float* dW1 = (const float*)d_in[9];
    const float* db1 = (const float*)d_in[10];
    const float* dW2 = (const float*)d_in[11];
    const float* db2 = (const float*)d_in[12];
    float* out = (float*)d_out;

    char* w = (char*)d_ws;
    auto alloc = [&](size_t bytes) {
        char* p = w;
        w += (bytes + 255) & ~(size_t)255;
        return p;
    };
    // workspace budget ~221 MB (proven envelope; 272 MB crashed in R7)
    int* cnt = (int*)alloc((size_t)N_NODES * 4);
    int* rs = (int*)alloc((size_t)N_NODES * 4);
    int* cursor = (int*)alloc((size_t)N_NODES * 4);
    int* bsums = (int*)alloc(512 * 4);
    float* dinv = (float*)alloc((size_t)N_NODES * 4);
    int2* csr_ew = (int2*)alloc((size_t)N_EDGES * 8);
    float* Uf = (float*)alloc((size_t)N_NODES * HDIM * 4);      // raw agg out (fp32)
    float* B = (float*)alloc((size_t)NPAD * HDIM * 4);          // hw fp32
    unsigned short* Ubf[NLAYERS];                               // raw agg out (bf16)
    for (int l = 0; l < NLAYERS; l++)
        Ubf[l] = (unsigned short*)alloc((size_t)NPAD * HDIM * 2);
    unsigned short* convWfh = (unsigned short*)alloc((size_t)NLAYERS * 16384 * 2);
    unsigned short* convWfl = (unsigned short*)alloc((size_t)NLAYERS * 16384 * 2);
    unsigned short* encWfh = (unsigned short*)alloc((size_t)NLAYERS * 32768 * 2);
    unsigned short* encWfl = (unsigned short*)alloc((size_t)NLAYERS * 32768 * 2);
    float* bnsum = (float*)alloc(128 * 4);
    float* bnsq = (float*)alloc(128 * 4);
    float* bnscaleAll = (float*)alloc(NLAYERS * 128 * 4);
    float* bnshiftAll = (float*)alloc(NLAYERS * 128 * 4);
    int* gcnt = (int*)alloc(256 * 4);
    int* gstart = (int*)alloc(256 * 4);
    float* psum = (float*)alloc(256 * 256 * 4);
    float* pooled = (float*)alloc(256 * 256 * 4);

    // CSR build + degree normalization
    hipMemsetAsync(cnt, 0, (size_t)N_NODES * 4, stream);
    k_count<<<(N_EDGES + 255) / 256, 256, 0, stream>>>(dst, cnt);
    k_dinv<<<(N_NODES + 255) / 256, 256, 0, stream>>>(cnt, dinv);
    int nb = (N_NODES + 255) / 256;  // 391
    k_scan_block<<<nb, 256, 0, stream>>>(cnt, rs, bsums);
    k_scan_sums<<<1, 512, 0, stream>>>(bsums, nb);
    k_scan_add<<<nb, 256, 0, stream>>>(rs, bsums, cursor);
    k_scatter<<<(N_EDGES + 255) / 256, 256, 0, stream>>>(src, dst, dinv, cursor, csr_ew);
    k_gbounds<<<1, 256, 0, stream>>>(batch, gstart, gcnt);

    // weight fragment permute + split (tiny)
    for (int l = 0; l < NLAYERS; l++) {
        k_wfrag<<<8, 256, 0, stream>>>(convW + (size_t)l * 16384, 128, 8,
                                       convWfh + (size_t)l * 16384,
                                       convWfl + (size_t)l * 16384);
        k_wfrag<<<16, 256, 0, stream>>>(encW + (size_t)l * 128 * 256, 256, 16,
                                        encWfh + (size_t)l * 32768,
                                        encWfl + (size_t)l * 32768);
    }

    for (int l = 0; l < NLAYERS; l++) {
        // hw = h @ convW_l  (h = x for l=0, else BN_{l-1}(Uf) fused in-register)
        if (l == 0)
            k_mfma<0, 0><<<dim3(NPAD / 128, 1), 256, 0, stream>>>(
                x, convWfh + (size_t)l * 16384, convWfl + (size_t)l * 16384,
                nullptr, nullptr, B, 128);
        else
            k_mfma<0, 1><<<dim3(NPAD / 128, 1), 256, 0, stream>>>(
                Uf, convWfh + (size_t)l * 16384, convWfl + (size_t)l * 16384,
                bnscaleAll + (l - 1) * 128, bnshiftAll + (l - 1) * 128, B, 128);
        // aggregate + bias -> Uf (fp32) + Ubf[l] (raw bf16)
        k_agg<<<N_NODES / 8, 256, 0, stream>>>((const float4*)B, rs, cnt, csr_ew, dinv,
                                               (const float4*)(convB + l * 128),
                                               (float4*)Uf, Ubf[l]);
        // BN stats
        hipMemsetAsync(bnsum, 0, 128 * 4, stream);
        hipMemsetAsync(bnsq, 0, 128 * 4, stream);
        k_bn_stats<<<512, 256, 0, stream>>>((const float4*)Uf, bnsum, bnsq);
        k_bn_finalize<<<1, 128, 0, stream>>>(bnsum, bnsq, gamma + l * 128, beta + l * 128,
                                             bnscaleAll + l * 128, bnshiftAll + l * 128);
    }

    // fused K=512 encoder GEMM + bias + ReLU + segment pool
    hipMemsetAsync(psum, 0, 256 * 256 * 4, stream);
    k_enc_pool<<<dim3(NPAD / 128, 2), 256, 0, stream>>>(
        Ubf[0], Ubf[1], Ubf[2], Ubf[3], encWfh, encWfl, bnscaleAll, bnshiftAll,
        encB, batch, psum);
    k_pool_fin<<<256, 256, 0, stream>>>(psum, gcnt, pooled);
    k_dec<<<256, 128, 0, stream>>>(pooled, dW1, db1, dW2, db2, out);
}

// Round 10
// 1186.720 us; speedup vs baseline: 8.8939x; 1.0852x over previous
//
#include <hip/hip_runtime.h>
#include <hip/hip_bf16.h>

#define N_NODES 100000
#define NPAD    100096   // 782 * 128
#define N_EDGES 1600000
#define HDIM 128
#define NLAYERS 4
#define NGRAPH 256
#define ENCDIM 256
#define EPS_BN 1e-5f

typedef __attribute__((ext_vector_type(8))) short bf16x8;
typedef __attribute__((ext_vector_type(4))) float f32x4;

__device__ __forceinline__ unsigned short f2bf(float v) {
    unsigned int u = __float_as_uint(v);
    u += 0x7FFFu + ((u >> 16) & 1u);
    return (unsigned short)(u >> 16);
}
__device__ __forceinline__ float bf2f(unsigned int lo16) {
    return __uint_as_float(lo16 << 16);
}

// ---------------- CSR build ----------------
__global__ void k_count(const int* __restrict__ dst, int* __restrict__ cnt) {
    int e = blockIdx.x * 256 + threadIdx.x;
    if (e < N_EDGES) atomicAdd(&cnt[dst[e]], 1);
}

__global__ void k_dinv(const int* __restrict__ cnt, float* __restrict__ dinv) {
    int n = blockIdx.x * 256 + threadIdx.x;
    if (n < N_NODES) dinv[n] = rsqrtf((float)cnt[n] + 1.0f);
}

__global__ void k_scan_block(const int* __restrict__ cnt, int* __restrict__ excl,
                             int* __restrict__ bsums) {
    __shared__ int s[256];
    int t = threadIdx.x;
    int i = blockIdx.x * 256 + t;
    int v = (i < N_NODES) ? cnt[i] : 0;
    s[t] = v;
    __syncthreads();
    for (int off = 1; off < 256; off <<= 1) {
        int x = 0;
        if (t >= off) x = s[t - off];
        __syncthreads();
        if (t >= off) s[t] += x;
        __syncthreads();
    }
    if (i < N_NODES) excl[i] = s[t] - v;
    if (t == 255) bsums[blockIdx.x] = s[255];
}

__global__ void k_scan_sums(int* __restrict__ bsums, int nb) {
    __shared__ int s[512];
    int t = threadIdx.x;
    int v = (t < nb) ? bsums[t] : 0;
    s[t] = v;
    __syncthreads();
    for (int off = 1; off < 512; off <<= 1) {
        int x = 0;
        if (t >= off) x = s[t - off];
        __syncthreads();
        if (t >= off) s[t] += x;
        __syncthreads();
    }
    if (t < nb) bsums[t] = s[t] - v;
}

__global__ void k_scan_add(int* __restrict__ excl, const int* __restrict__ bsums,
                           int* __restrict__ cursor) {
    int i = blockIdx.x * 256 + threadIdx.x;
    if (i < N_NODES) {
        int v = excl[i] + bsums[blockIdx.x];
        excl[i] = v;
        cursor[i] = v;
    }
}

__global__ void k_scatter(const int* __restrict__ src, const int* __restrict__ dst,
                          const float* __restrict__ dinv, int* __restrict__ cursor,
                          int2* __restrict__ csr_ew) {
    int e = blockIdx.x * 256 + threadIdx.x;
    if (e < N_EDGES) {
        int d = dst[e];
        int s = src[e];
        int p = atomicAdd(&cursor[d], 1);
        int2 v;
        v.x = s;
        v.y = __float_as_int(dinv[s] * dinv[d]);
        csr_ew[p] = v;
    }
}

// ---------------- graph bounds via binary search (batch is sorted) ----------------
__global__ void k_gbounds(const int* __restrict__ batch, int* __restrict__ gstart,
                          int* __restrict__ gcnt) {
    __shared__ int s[257];
    int g = threadIdx.x;  // 256 threads
    int lo = 0, hi = N_NODES;
    while (lo < hi) {
        int mid = (lo + hi) >> 1;
        if (batch[mid] < g) lo = mid + 1; else hi = mid;
    }
    s[g] = lo;
    if (g == 255) s[256] = N_NODES;
    __syncthreads();
    gstart[g] = s[g];
    gcnt[g] = s[g + 1] - s[g];
}

// ---------------- weight -> MFMA B-fragment order, split hi/lo ----------------
// F[((nt*4 + ks)*64 + lane)*8 + j] = W[(ks*32 + (lane>>4)*8 + j)*ldw + nt*16 + (lane&15)]
__global__ void k_wfrag(const float* __restrict__ W, int ldw, int ntiles,
                        unsigned short* __restrict__ Fh, unsigned short* __restrict__ Fl) {
    int t = blockIdx.x * 256 + threadIdx.x;
    if (t >= ntiles * 256) return;
    int lane = t & 63, ks = (t >> 6) & 3, nt = t >> 8;
    int r16 = lane & 15, kq = lane >> 4;
    unsigned short h[8], l[8];
#pragma unroll
    for (int j = 0; j < 8; j++) {
        float w = W[(size_t)(ks * 32 + kq * 8 + j) * ldw + nt * 16 + r16];
        unsigned short hh = f2bf(w);
        h[j] = hh;
        l[j] = f2bf(w - bf2f(hh));
    }
    ((ushort4*)(Fh + (size_t)t * 8))[0] = make_ushort4(h[0], h[1], h[2], h[3]);
    ((ushort4*)(Fh + (size_t)t * 8))[1] = make_ushort4(h[4], h[5], h[6], h[7]);
    ((ushort4*)(Fl + (size_t)t * 8))[0] = make_ushort4(l[0], l[1], l[2], l[3]);
    ((ushort4*)(Fl + (size_t)t * 8))[1] = make_ushort4(l[4], l[5], l[6], l[7]);
}

// ---------------- helper: load fp32 A + optional BN+ReLU + hi/lo split ----------
__device__ __forceinline__ void load_a_frag(const float* __restrict__ A, size_t row,
                                            bool ok, int kq, int ks,
                                            const float* __restrict__ scale,
                                            const float* __restrict__ shift, int useBN,
                                            bf16x8& hv_out, bf16x8& lv_out) {
    float4 v0 = make_float4(0.f, 0.f, 0.f, 0.f);
    float4 v1 = make_float4(0.f, 0.f, 0.f, 0.f);
    if (ok) {
        const float* pa = A + row * 128 + kq * 8 + ks * 32;
        v0 = *(const float4*)pa;
        v1 = *(const float4*)(pa + 4);
    }
    if (useBN) {
        int f0 = ks * 32 + kq * 8;
        float4 sc0 = *(const float4*)&scale[f0];
        float4 sc1 = *(const float4*)&scale[f0 + 4];
        float4 sh0 = *(const float4*)&shift[f0];
        float4 sh1 = *(const float4*)&shift[f0 + 4];
        v0.x = fmaxf(fmaf(v0.x, sc0.x, sh0.x), 0.f);
        v0.y = fmaxf(fmaf(v0.y, sc0.y, sh0.y), 0.f);
        v0.z = fmaxf(fmaf(v0.z, sc0.z, sh0.z), 0.f);
        v0.w = fmaxf(fmaf(v0.w, sc0.w, sh0.w), 0.f);
        v1.x = fmaxf(fmaf(v1.x, sc1.x, sh1.x), 0.f);
        v1.y = fmaxf(fmaf(v1.y, sc1.y, sh1.y), 0.f);
        v1.z = fmaxf(fmaf(v1.z, sc1.z, sh1.z), 0.f);
        v1.w = fmaxf(fmaf(v1.w, sc1.w, sh1.w), 0.f);
        if (!ok) {
            v0 = make_float4(0.f, 0.f, 0.f, 0.f);
            v1 = make_float4(0.f, 0.f, 0.f, 0.f);
        }
    }
    float vv[8] = {v0.x, v0.y, v0.z, v0.w, v1.x, v1.y, v1.z, v1.w};
    bf16x8 hv, lv;
#pragma unroll
    for (int j = 0; j < 8; j++) {
        unsigned short hh = f2bf(vv[j]);
        hv[j] = (short)hh;
        lv[j] = (short)f2bf(vv[j] - bf2f(hh));
    }
    hv_out = hv;
    lv_out = lv;
}

// ---- helper: load raw-bf16 A, BN+ReLU in fp32, round to SINGLE bf16 ------------
// (encoder path; A is already bf16-rounded so a second 2^-9 rounding is below the
//  existing noise floor — saves 64 VGPRs + 1/3 of MFMAs vs hi/lo)
__device__ __forceinline__ bf16x8 bn_bf_frag(const unsigned short* __restrict__ Ub,
                                             size_t row, bool ok, int kq, int ks,
                                             const float* __restrict__ scale,
                                             const float* __restrict__ shift) {
    bf16x8 out;
    if (ok) {
        bf16x8 raw = *reinterpret_cast<const bf16x8*>(Ub + row * 128 + ks * 32 + kq * 8);
        int f0 = ks * 32 + kq * 8;
        float4 sc0 = *(const float4*)&scale[f0];
        float4 sc1 = *(const float4*)&scale[f0 + 4];
        float4 sh0 = *(const float4*)&shift[f0];
        float4 sh1 = *(const float4*)&shift[f0 + 4];
        float scv[8] = {sc0.x, sc0.y, sc0.z, sc0.w, sc1.x, sc1.y, sc1.z, sc1.w};
        float shv[8] = {sh0.x, sh0.y, sh0.z, sh0.w, sh1.x, sh1.y, sh1.z, sh1.w};
#pragma unroll
        for (int j = 0; j < 8; j++) {
            float v = fmaxf(fmaf(bf2f((unsigned short)raw[j]), scv[j], shv[j]), 0.f);
            out[j] = (short)f2bf(v);
        }
    } else {
#pragma unroll
        for (int j = 0; j < 8; j++) out[j] = 0;
    }
    return out;
}

// ---------------- split-bf16 MFMA GEMM, fp32 A with optional fused BN+ReLU ------
template <int ACC, int BN>
__global__ __launch_bounds__(256) void k_mfma(const float* __restrict__ A,
                                              const unsigned short* __restrict__ Fh,
                                              const unsigned short* __restrict__ Fl,
                                              const float* __restrict__ scale,
                                              const float* __restrict__ shift,
                                              float* __restrict__ C, int ldc) {
    int lane = threadIdx.x & 63;
    int wid = threadIdx.x >> 6;
    int r16 = lane & 15, kq = lane >> 4;
    size_t mrow0 = (size_t)blockIdx.x * 128 + wid * 32;
    int colOff = blockIdx.y * 128;
    int ntBase = blockIdx.y * 8;

    bf16x8 ah[2][4], al[2][4];
#pragma unroll
    for (int mt = 0; mt < 2; mt++) {
        size_t row = mrow0 + mt * 16 + r16;
        bool ok = row < N_NODES;
#pragma unroll
        for (int ks = 0; ks < 4; ks++)
            load_a_frag(A, row, ok, kq, ks, scale, shift, BN, ah[mt][ks], al[mt][ks]);
    }

    f32x4 acc[2][8];
#pragma unroll
    for (int mt = 0; mt < 2; mt++)
#pragma unroll
        for (int nt = 0; nt < 8; nt++) acc[mt][nt] = (f32x4){0.f, 0.f, 0.f, 0.f};

#pragma unroll
    for (int nt = 0; nt < 8; nt++) {
        const unsigned short* pbh = Fh + ((size_t)(ntBase + nt) * 4 * 64 + lane) * 8;
        const unsigned short* pbl = Fl + ((size_t)(ntBase + nt) * 4 * 64 + lane) * 8;
        bf16x8 bh[4], bl[4];
#pragma unroll
        for (int ks = 0; ks < 4; ks++) {
            bh[ks] = *reinterpret_cast<const bf16x8*>(pbh + ks * 512);
            bl[ks] = *reinterpret_cast<const bf16x8*>(pbl + ks * 512);
        }
#pragma unroll
        for (int mt = 0; mt < 2; mt++)
#pragma unroll
            for (int ks = 0; ks < 4; ks++) {
                acc[mt][nt] = __builtin_amdgcn_mfma_f32_16x16x32_bf16(ah[mt][ks], bl[ks],
                                                                     acc[mt][nt], 0, 0, 0);
                acc[mt][nt] = __builtin_amdgcn_mfma_f32_16x16x32_bf16(al[mt][ks], bh[ks],
                                                                     acc[mt][nt], 0, 0, 0);
                acc[mt][nt] = __builtin_amdgcn_mfma_f32_16x16x32_bf16(ah[mt][ks], bh[ks],
                                                                     acc[mt][nt], 0, 0, 0);
            }
    }

#pragma unroll
    for (int mt = 0; mt < 2; mt++)
#pragma unroll
        for (int nt = 0; nt < 8; nt++)
#pragma unroll
            for (int r = 0; r < 4; r++) {
                size_t row = mrow0 + mt * 16 + kq * 4 + r;
                float* cp = C + row * ldc + colOff + nt * 16 + r16;
                float v = acc[mt][nt][r];
                if (ACC) v += *cp;
                *cp = v;
            }
}

// ------ fused K=512 encoder GEMM (bf16 A, split-bf16 W) + bias + ReLU + pool -----
__global__ __launch_bounds__(256) void k_enc_pool(
    const unsigned short* __restrict__ Ub0, const unsigned short* __restrict__ Ub1,
    const unsigned short* __restrict__ Ub2, const unsigned short* __restrict__ Ub3,
    const unsigned short* __restrict__ Fh, const unsigned short* __restrict__ Fl,
    const float* __restrict__ scaleAll, const float* __restrict__ shiftAll,
    const float* __restrict__ encB, const int* __restrict__ batch,
    float* __restrict__ psum) {
    int lane = threadIdx.x & 63;
    int wid = threadIdx.x >> 6;
    int r16 = lane & 15, kq = lane >> 4;
    size_t brow0 = (size_t)blockIdx.x * 128;
    size_t mrow0 = brow0 + wid * 32;
    int colOff = blockIdx.y * 128;
    int ntBase = blockIdx.y * 8;

    __shared__ int batch_lds[128];
    if (threadIdx.x < 128) {
        size_t row = brow0 + threadIdx.x;
        batch_lds[threadIdx.x] = (row < N_NODES) ? batch[row] : -1;
    }
    __syncthreads();

    f32x4 acc[2][8];
#pragma unroll
    for (int mt = 0; mt < 2; mt++)
#pragma unroll
        for (int nt = 0; nt < 8; nt++) acc[mt][nt] = (f32x4){0.f, 0.f, 0.f, 0.f};

    const unsigned short* Ubs[4] = {Ub0, Ub1, Ub2, Ub3};
#pragma unroll 1
    for (int l = 0; l < 4; l++) {
        const unsigned short* Ub = Ubs[l];
        const float* scale = scaleAll + l * 128;
        const float* shift = shiftAll + l * 128;
        bf16x8 ah[2][4];
#pragma unroll
        for (int mt = 0; mt < 2; mt++) {
            size_t row = mrow0 + mt * 16 + r16;
            bool ok = row < N_NODES;
#pragma unroll
            for (int ks = 0; ks < 4; ks++)
                ah[mt][ks] = bn_bf_frag(Ub, row, ok, kq, ks, scale, shift);
        }
        const unsigned short* Fhl = Fh + (size_t)l * 32768;
        const unsigned short* Fll = Fl + (size_t)l * 32768;
#pragma unroll
        for (int nt = 0; nt < 8; nt++) {
            const unsigned short* pbh = Fhl + ((size_t)(ntBase + nt) * 4 * 64 + lane) * 8;
            const unsigned short* pbl = Fll + ((size_t)(ntBase + nt) * 4 * 64 + lane) * 8;
            bf16x8 bh[4], bl[4];
#pragma unroll
            for (int ks = 0; ks < 4; ks++) {
                bh[ks] = *reinterpret_cast<const bf16x8*>(pbh + ks * 512);
                bl[ks] = *reinterpret_cast<const bf16x8*>(pbl + ks * 512);
            }
#pragma unroll
            for (int mt = 0; mt < 2; mt++)
#pragma unroll
                for (int ks = 0; ks < 4; ks++) {
                    acc[mt][nt] = __builtin_amdgcn_mfma_f32_16x16x32_bf16(
                        ah[mt][ks], bl[ks], acc[mt][nt], 0, 0, 0);
                    acc[mt][nt] = __builtin_amdgcn_mfma_f32_16x16x32_bf16(
                        ah[mt][ks], bh[ks], acc[mt][nt], 0, 0, 0);
                }
        }
    }

    // relu(acc + encB), pads zeroed
    float bias[8];
#pragma unroll
    for (int nt = 0; nt < 8; nt++) bias[nt] = encB[colOff + nt * 16 + r16];
#pragma unroll
    for (int mt = 0; mt < 2; mt++)
#pragma unroll
        for (int r = 0; r < 4; r++) {
            bool valid = batch_lds[wid * 32 + mt * 16 + kq * 4 + r] >= 0;
#pragma unroll
            for (int nt = 0; nt < 8; nt++)
                acc[mt][nt][r] = valid ? fmaxf(acc[mt][nt][r] + bias[nt], 0.f) : 0.f;
        }

    // segment pool (batch sorted; block spans few graphs)
    int lastIdx = (int)((N_NODES - 1 - brow0) < 127 ? (N_NODES - 1 - brow0) : 127);
    int g0 = batch_lds[0];
    int g1 = batch_lds[lastIdx];
    __shared__ float sred[4][128];
    for (int g = g0; g <= g1; ++g) {
        float s[8];
#pragma unroll
        for (int nt = 0; nt < 8; nt++) s[nt] = 0.f;
#pragma unroll
        for (int mt = 0; mt < 2; mt++)
#pragma unroll
            for (int r = 0; r < 4; r++) {
                bool m = batch_lds[wid * 32 + mt * 16 + kq * 4 + r] == g;
                if (m) {
#pragma unroll
                    for (int nt = 0; nt < 8; nt++) s[nt] += acc[mt][nt][r];
                }
            }
#pragma unroll
        for (int nt = 0; nt < 8; nt++) {
            s[nt] += __shfl_xor(s[nt], 16);
            s[nt] += __shfl_xor(s[nt], 32);
        }
        if (lane < 16) {
#pragma unroll
            for (int nt = 0; nt < 8; nt++) sred[wid][nt * 16 + r16] = s[nt];
        }
        __syncthreads();
        if (threadIdx.x < 128) {
            float tot = sred[0][threadIdx.x] + sred[1][threadIdx.x] +
                        sred[2][threadIdx.x] + sred[3][threadIdx.x];
            atomicAdd(&psum[(size_t)g * ENCDIM + colOff + threadIdx.x], tot);
        }
        __syncthreads();
    }
}

// ------ aggregation: Uf(fp32) + Ub(raw bf16) <- S * hw + bias --------------------
__global__ __launch_bounds__(256) void k_agg(const float4* __restrict__ hw4,
                                             const int* __restrict__ rs,
                                             const int* __restrict__ cnt,
                                             const int2* __restrict__ csr_ew,
                                             const float* __restrict__ dinv,
                                             const float4* __restrict__ bias4,
                                             float4* __restrict__ Uf4,
                                             unsigned short* __restrict__ Ub) {
    int n = blockIdx.x * 8 + (threadIdx.x >> 5);
    int lane = threadIdx.x & 31;
    if (n >= N_NODES) return;
    float d = dinv[n];
    float dd = d * d;
    float4 self = hw4[(size_t)n * 32 + lane];
    float4 b = bias4[lane];
    float4 acc;
    acc.x = fmaf(dd, self.x, b.x);
    acc.y = fmaf(dd, self.y, b.y);
    acc.z = fmaf(dd, self.z, b.z);
    acc.w = fmaf(dd, self.w, b.w);
    int s0 = rs[n];
    int c = cnt[n];
    int e = 0;
    for (; e + 8 <= c; e += 8) {
        int2 ee[8];
        float4 vv[8];
#pragma unroll
        for (int u = 0; u < 8; u++) ee[u] = csr_ew[s0 + e + u];
#pragma unroll
        for (int u = 0; u < 8; u++) vv[u] = hw4[(size_t)ee[u].x * 32 + lane];
#pragma unroll
        for (int u = 0; u < 8; u++) {
            float w = __int_as_float(ee[u].y);
            acc.x = fmaf(w, vv[u].x, acc.x);
            acc.y = fmaf(w, vv[u].y, acc.y);
            acc.z = fmaf(w, vv[u].z, acc.z);
            acc.w = fmaf(w, vv[u].w, acc.w);
        }
    }
    for (; e < c; e++) {
        int2 ee = csr_ew[s0 + e];
        float4 v = hw4[(size_t)ee.x * 32 + lane];
        float w = __int_as_float(ee.y);
        acc.x = fmaf(w, v.x, acc.x); acc.y = fmaf(w, v.y, acc.y);
        acc.z = fmaf(w, v.z, acc.z); acc.w = fmaf(w, v.w, acc.w);
    }
    Uf4[(size_t)n * 32 + lane] = acc;
    ushort4 bv;
    bv.x = f2bf(acc.x);
    bv.y = f2bf(acc.y);
    bv.z = f2bf(acc.z);
    bv.w = f2bf(acc.w);
    *(ushort4*)(Ub + (size_t)n * 128 + lane * 4) = bv;
}

// ---------------- BN stats on fp32 Uf ----------------
__global__ __launch_bounds__(256) void k_bn_stats(const float4* __restrict__ Uf4,
                                                  float* __restrict__ sum,
                                                  float* __restrict__ sq) {
    int c4 = threadIdx.x & 31;  // float4 column = features 4*c4..4*c4+3
    int y = threadIdx.x >> 5;   // 8 row-groups
    float4 s = make_float4(0.f, 0.f, 0.f, 0.f);
    float4 q = make_float4(0.f, 0.f, 0.f, 0.f);
    for (size_t n = (size_t)blockIdx.x * 8 + y; n < N_NODES; n += (size_t)gridDim.x * 8) {
        float4 v = Uf4[n * 32 + c4];
        s.x += v.x; s.y += v.y; s.z += v.z; s.w += v.w;
        q.x = fmaf(v.x, v.x, q.x); q.y = fmaf(v.y, v.y, q.y);
        q.z = fmaf(v.z, v.z, q.z); q.w = fmaf(v.w, v.w, q.w);
    }
    __shared__ float4 ls[256], lq[256];
    ls[threadIdx.x] = s;
    lq[threadIdx.x] = q;
    __syncthreads();
    if (y == 0) {
#pragma unroll
        for (int yy = 1; yy < 8; yy++) {
            float4 a = ls[yy * 32 + c4], b = lq[yy * 32 + c4];
            s.x += a.x; s.y += a.y; s.z += a.z; s.w += a.w;
            q.x += b.x; q.y += b.y; q.z += b.z; q.w += b.w;
        }
        atomicAdd(&sum[c4 * 4 + 0], s.x);
        atomicAdd(&sum[c4 * 4 + 1], s.y);
        atomicAdd(&sum[c4 * 4 + 2], s.z);
        atomicAdd(&sum[c4 * 4 + 3], s.w);
        atomicAdd(&sq[c4 * 4 + 0], q.x);
        atomicAdd(&sq[c4 * 4 + 1], q.y);
        atomicAdd(&sq[c4 * 4 + 2], q.z);
        atomicAdd(&sq[c4 * 4 + 3], q.w);
    }
}

__global__ void k_bn_finalize(const float* __restrict__ sum, const float* __restrict__ sq,
                              const float* __restrict__ gamma, const float* __restrict__ beta,
                              float* __restrict__ scale, float* __restrict__ shift) {
    int f = threadIdx.x;
    float mu = sum[f] * (1.0f / N_NODES);
    float var = sq[f] * (1.0f / N_NODES) - mu * mu;
    float s = rsqrtf(var + EPS_BN) * gamma[f];
    scale[f] = s;
    shift[f] = beta[f] - mu * s;
}

// ---------------- decoder (mean-divide folded in) ----------------
__global__ __launch_bounds__(128) void k_dec(const float* __restrict__ psum,
                                             const int* __restrict__ gcnt,
                                             const float* __restrict__ W1,
                                             const float* __restrict__ b1,
                                             const float* __restrict__ W2,
                                             const float* __restrict__ b2,
                                             float* __restrict__ out) {
    int g = blockIdx.x;
    int j = threadIdx.x;
    float inv = 1.0f / fmaxf((float)gcnt[g], 1.0f);
    const float* p = &psum[g * ENCDIM];
    float acc = b1[j];
    for (int k = 0; k < ENCDIM; k++) acc = fmaf(p[k] * inv, W1[k * 128 + j], acc);
    float h = fmaxf(acc, 0.f) * W2[j];
    for (int off = 32; off; off >>= 1) h += __shfl_down(h, off);
    __shared__ float red[2];
    if ((j & 63) == 0) red[j >> 6] = h;
    __syncthreads();
    if (j == 0) out[g] = red[0] + red[1] + b2[0];
}

extern "C" void kernel_launch(void* const* d_in, const int* in_sizes, int n_in,
                              void* d_out, int out_size, void* d_ws, size_t ws_size,
                              hipStream_t stream) {
    const float* x = (const float*)d_in[0];
    const int* ei = (const int*)d_in[1];
    const int* src = ei;
    const int* dst = ei + N_EDGES;
    const int* batch = (const int*)d_in[2];
    const float* convW = (const float*)d_in[3];
    const float* convB = (const float*)d_in[4];
    const float* gamma = (const float*)d_in[5];
    const float* beta = (const float*)d_in[6];
    const float* encW = (const float*)d_in[7];
    const float* encB = (const float*)d_in[8];
    const float* dW1 = (const float*)d_in[9];
    const float* db1 = (const float*)d_in[10];
    const float* dW2 = (const float*)d_in[11];
    const float* db2 = (const float*)d_in[12];
    float* out = (float*)d_out;

    char* w = (char*)d_ws;
    auto alloc = [&](size_t bytes) {
        char* p = w;
        w += (bytes + 255) & ~(size_t)255;
        return p;
    };
    // workspace budget ~221 MB (proven envelope; 272 MB crashed in R7)
    int* cnt = (int*)alloc((size_t)N_NODES * 4);
    int* rs = (int*)alloc((size_t)N_NODES * 4);
    int* cursor = (int*)alloc((size_t)N_NODES * 4);
    int* bsums = (int*)alloc(512 * 4);
    float* dinv = (float*)alloc((size_t)N_NODES * 4);
    int2* csr_ew = (int2*)alloc((size_t)N_EDGES * 8);
    float* Uf = (float*)alloc((size_t)N_NODES * HDIM * 4);      // raw agg out (fp32)
    float* B = (float*)alloc((size_t)NPAD * HDIM * 4);          // hw fp32
    unsigned short* Ubf[NLAYERS];                               // raw agg out (bf16)
    for (int l = 0; l < NLAYERS; l++)
        Ubf[l] = (unsigned short*)alloc((size_t)NPAD * HDIM * 2);
    unsigned short* convWfh = (unsigned short*)alloc((size_t)NLAYERS * 16384 * 2);
    unsigned short* convWfl = (unsigned short*)alloc((size_t)NLAYERS * 16384 * 2);
    unsigned short* encWfh = (unsigned short*)alloc((size_t)NLAYERS * 32768 * 2);
    unsigned short* encWfl = (unsigned short*)alloc((size_t)NLAYERS * 32768 * 2);
    float* bnsumAll = (float*)alloc(NLAYERS * 128 * 4);
    float* bnsqAll = (float*)alloc(NLAYERS * 128 * 4);
    float* bnscaleAll = (float*)alloc(NLAYERS * 128 * 4);
    float* bnshiftAll = (float*)alloc(NLAYERS * 128 * 4);
    int* gcnt = (int*)alloc(256 * 4);
    int* gstart = (int*)alloc(256 * 4);
    float* psum = (float*)alloc(256 * 256 * 4);

    // CSR build + degree normalization
    hipMemsetAsync(cnt, 0, (size_t)N_NODES * 4, stream);
    hipMemsetAsync(bnsumAll, 0, NLAYERS * 128 * 4, stream);
    hipMemsetAsync(bnsqAll, 0, NLAYERS * 128 * 4, stream);
    hipMemsetAsync(psum, 0, 256 * 256 * 4, stream);
    k_count<<<(N_EDGES + 255) / 256, 256, 0, stream>>>(dst, cnt);
    k_dinv<<<(N_NODES + 255) / 256, 256, 0, stream>>>(cnt, dinv);
    int nb = (N_NODES + 255) / 256;  // 391
    k_scan_block<<<nb, 256, 0, stream>>>(cnt, rs, bsums);
    k_scan_sums<<<1, 512, 0, stream>>>(bsums, nb);
    k_scan_add<<<nb, 256, 0, stream>>>(rs, bsums, cursor);
    k_scatter<<<(N_EDGES + 255) / 256, 256, 0, stream>>>(src, dst, dinv, cursor, csr_ew);
    k_gbounds<<<1, 256, 0, stream>>>(batch, gstart, gcnt);

    // weight fragment permute + split (tiny)
    for (int l = 0; l < NLAYERS; l++) {
        k_wfrag<<<8, 256, 0, stream>>>(convW + (size_t)l * 16384, 128, 8,
                                       convWfh + (size_t)l * 16384,
                                       convWfl + (size_t)l * 16384);
        k_wfrag<<<16, 256, 0, stream>>>(encW + (size_t)l * 128 * 256, 256, 16,
                                        encWfh + (size_t)l * 32768,
                                        encWfl + (size_t)l * 32768);
    }

    for (int l = 0; l < NLAYERS; l++) {
        // hw = h @ convW_l  (h = x for l=0, else BN_{l-1}(Uf) fused in-register)
        if (l == 0)
            k_mfma<0, 0><<<dim3(NPAD / 128, 1), 256, 0, stream>>>(
                x, convWfh + (size_t)l * 16384, convWfl + (size_t)l * 16384,
                nullptr, nullptr, B, 128);
        else
            k_mfma<0, 1><<<dim3(NPAD / 128, 1), 256, 0, stream>>>(
                Uf, convWfh + (size_t)l * 16384, convWfl + (size_t)l * 16384,
                bnscaleAll + (l - 1) * 128, bnshiftAll + (l - 1) * 128, B, 128);
        // aggregate + bias -> Uf (fp32) + Ubf[l] (raw bf16)
        k_agg<<<N_NODES / 8, 256, 0, stream>>>((const float4*)B, rs, cnt, csr_ew, dinv,
                                               (const float4*)(convB + l * 128),
                                               (float4*)Uf, Ubf[l]);
        // BN stats
        k_bn_stats<<<512, 256, 0, stream>>>((const float4*)Uf, bnsumAll + l * 128,
                                            bnsqAll + l * 128);
        k_bn_finalize<<<1, 128, 0, stream>>>(bnsumAll + l * 128, bnsqAll + l * 128,
                                             gamma + l * 128, beta + l * 128,
                                             bnscaleAll + l * 128, bnshiftAll + l * 128);
    }

    // fused K=512 encoder GEMM + bias + ReLU + segment pool
    k_enc_pool<<<dim3(NPAD / 128, 2), 256, 0, stream>>>(
        Ubf[0], Ubf[1], Ubf[2], Ubf[3], encWfh, encWfl, bnscaleAll, bnshiftAll,
        encB, batch, psum);
    k_dec<<<256, 128, 0, stream>>>(psum, gcnt, dW1, db1, dW2, db2, out);
}

// Round 11
// 975.270 us; speedup vs baseline: 10.8221x; 1.2168x over previous
//
#include <hip/hip_runtime.h>
#include <hip/hip_bf16.h>

#define N_NODES 100000
#define NPAD    100096   // 782 * 128
#define N_EDGES 1600000
#define HDIM 128
#define NLAYERS 4
#define NGRAPH 256
#define ENCDIM 256
#define EPS_BN 1e-5f

typedef __attribute__((ext_vector_type(8))) short bf16x8;
typedef __attribute__((ext_vector_type(4))) float f32x4;

__device__ __forceinline__ unsigned short f2bf(float v) {
    unsigned int u = __float_as_uint(v);
    u += 0x7FFFu + ((u >> 16) & 1u);
    return (unsigned short)(u >> 16);
}
__device__ __forceinline__ float bf2f(unsigned int lo16) {
    return __uint_as_float(lo16 << 16);
}

// ---------------- CSR build ----------------
__global__ void k_count(const int* __restrict__ dst, int* __restrict__ cnt) {
    int e = blockIdx.x * 256 + threadIdx.x;
    if (e < N_EDGES) atomicAdd(&cnt[dst[e]], 1);
}

__global__ void k_dinv(const int* __restrict__ cnt, float* __restrict__ dinv) {
    int n = blockIdx.x * 256 + threadIdx.x;
    if (n < N_NODES) dinv[n] = rsqrtf((float)cnt[n] + 1.0f);
}

__global__ void k_scan_block(const int* __restrict__ cnt, int* __restrict__ excl,
                             int* __restrict__ bsums) {
    __shared__ int s[256];
    int t = threadIdx.x;
    int i = blockIdx.x * 256 + t;
    int v = (i < N_NODES) ? cnt[i] : 0;
    s[t] = v;
    __syncthreads();
    for (int off = 1; off < 256; off <<= 1) {
        int x = 0;
        if (t >= off) x = s[t - off];
        __syncthreads();
        if (t >= off) s[t] += x;
        __syncthreads();
    }
    if (i < N_NODES) excl[i] = s[t] - v;
    if (t == 255) bsums[blockIdx.x] = s[255];
}

__global__ void k_scan_sums(int* __restrict__ bsums, int nb) {
    __shared__ int s[512];
    int t = threadIdx.x;
    int v = (t < nb) ? bsums[t] : 0;
    s[t] = v;
    __syncthreads();
    for (int off = 1; off < 512; off <<= 1) {
        int x = 0;
        if (t >= off) x = s[t - off];
        __syncthreads();
        if (t >= off) s[t] += x;
        __syncthreads();
    }
    if (t < nb) bsums[t] = s[t] - v;
}

__global__ void k_scan_add(int* __restrict__ excl, const int* __restrict__ bsums,
                           int* __restrict__ cursor) {
    int i = blockIdx.x * 256 + threadIdx.x;
    if (i < N_NODES) {
        int v = excl[i] + bsums[blockIdx.x];
        excl[i] = v;
        cursor[i] = v;
    }
}

__global__ void k_scatter(const int* __restrict__ src, const int* __restrict__ dst,
                          const float* __restrict__ dinv, int* __restrict__ cursor,
                          int2* __restrict__ csr_ew) {
    int e = blockIdx.x * 256 + threadIdx.x;
    if (e < N_EDGES) {
        int d = dst[e];
        int s = src[e];
        int p = atomicAdd(&cursor[d], 1);
        int2 v;
        v.x = s;
        v.y = __float_as_int(dinv[s] * dinv[d]);
        csr_ew[p] = v;
    }
}

// ---------------- graph bounds via binary search (batch is sorted) ----------------
__global__ void k_gbounds(const int* __restrict__ batch, int* __restrict__ gstart,
                          int* __restrict__ gcnt) {
    __shared__ int s[257];
    int g = threadIdx.x;  // 256 threads
    int lo = 0, hi = N_NODES;
    while (lo < hi) {
        int mid = (lo + hi) >> 1;
        if (batch[mid] < g) lo = mid + 1; else hi = mid;
    }
    s[g] = lo;
    if (g == 255) s[256] = N_NODES;
    __syncthreads();
    gstart[g] = s[g];
    gcnt[g] = s[g + 1] - s[g];
}

// ---------------- weight -> MFMA B-fragment order, split hi/lo ----------------
// F[((nt*4 + ks)*64 + lane)*8 + j] = W[(ks*32 + (lane>>4)*8 + j)*ldw + nt*16 + (lane&15)]
__global__ void k_wfrag(const float* __restrict__ W, int ldw, int ntiles,
                        unsigned short* __restrict__ Fh, unsigned short* __restrict__ Fl) {
    int t = blockIdx.x * 256 + threadIdx.x;
    if (t >= ntiles * 256) return;
    int lane = t & 63, ks = (t >> 6) & 3, nt = t >> 8;
    int r16 = lane & 15, kq = lane >> 4;
    unsigned short h[8], l[8];
#pragma unroll
    for (int j = 0; j < 8; j++) {
        float w = W[(size_t)(ks * 32 + kq * 8 + j) * ldw + nt * 16 + r16];
        unsigned short hh = f2bf(w);
        h[j] = hh;
        l[j] = f2bf(w - bf2f(hh));
    }
    ((ushort4*)(Fh + (size_t)t * 8))[0] = make_ushort4(h[0], h[1], h[2], h[3]);
    ((ushort4*)(Fh + (size_t)t * 8))[1] = make_ushort4(h[4], h[5], h[6], h[7]);
    ((ushort4*)(Fl + (size_t)t * 8))[0] = make_ushort4(l[0], l[1], l[2], l[3]);
    ((ushort4*)(Fl + (size_t)t * 8))[1] = make_ushort4(l[4], l[5], l[6], l[7]);
}

// ---------------- helper: load fp32 A + optional BN+ReLU + hi/lo split ----------
__device__ __forceinline__ void load_a_frag(const float* __restrict__ A, size_t row,
                                            bool ok, int kq, int ks,
                                            const float* __restrict__ scale,
                                            const float* __restrict__ shift, int useBN,
                                            bf16x8& hv_out, bf16x8& lv_out) {
    float4 v0 = make_float4(0.f, 0.f, 0.f, 0.f);
    float4 v1 = make_float4(0.f, 0.f, 0.f, 0.f);
    if (ok) {
        const float* pa = A + row * 128 + kq * 8 + ks * 32;
        v0 = *(const float4*)pa;
        v1 = *(const float4*)(pa + 4);
    }
    if (useBN) {
        int f0 = ks * 32 + kq * 8;
        float4 sc0 = *(const float4*)&scale[f0];
        float4 sc1 = *(const float4*)&scale[f0 + 4];
        float4 sh0 = *(const float4*)&shift[f0];
        float4 sh1 = *(const float4*)&shift[f0 + 4];
        v0.x = fmaxf(fmaf(v0.x, sc0.x, sh0.x), 0.f);
        v0.y = fmaxf(fmaf(v0.y, sc0.y, sh0.y), 0.f);
        v0.z = fmaxf(fmaf(v0.z, sc0.z, sh0.z), 0.f);
        v0.w = fmaxf(fmaf(v0.w, sc0.w, sh0.w), 0.f);
        v1.x = fmaxf(fmaf(v1.x, sc1.x, sh1.x), 0.f);
        v1.y = fmaxf(fmaf(v1.y, sc1.y, sh1.y), 0.f);
        v1.z = fmaxf(fmaf(v1.z, sc1.z, sh1.z), 0.f);
        v1.w = fmaxf(fmaf(v1.w, sc1.w, sh1.w), 0.f);
        if (!ok) {
            v0 = make_float4(0.f, 0.f, 0.f, 0.f);
            v1 = make_float4(0.f, 0.f, 0.f, 0.f);
        }
    }
    float vv[8] = {v0.x, v0.y, v0.z, v0.w, v1.x, v1.y, v1.z, v1.w};
    bf16x8 hv, lv;
#pragma unroll
    for (int j = 0; j < 8; j++) {
        unsigned short hh = f2bf(vv[j]);
        hv[j] = (short)hh;
        lv[j] = (short)f2bf(vv[j] - bf2f(hh));
    }
    hv_out = hv;
    lv_out = lv;
}

// ------ conv GEMM: split-bf16 MFMA, fp32 A (opt fused BN+ReLU), bf16 C out -------
template <int BN>
__global__ __launch_bounds__(256) void k_mfma(const float* __restrict__ A,
                                              const unsigned short* __restrict__ Fh,
                                              const unsigned short* __restrict__ Fl,
                                              const float* __restrict__ scale,
                                              const float* __restrict__ shift,
                                              unsigned short* __restrict__ Cb) {
    int lane = threadIdx.x & 63;
    int wid = threadIdx.x >> 6;
    int r16 = lane & 15, kq = lane >> 4;
    size_t mrow0 = (size_t)blockIdx.x * 128 + wid * 32;

    bf16x8 ah[2][4], al[2][4];
#pragma unroll
    for (int mt = 0; mt < 2; mt++) {
        size_t row = mrow0 + mt * 16 + r16;
        bool ok = row < N_NODES;
#pragma unroll
        for (int ks = 0; ks < 4; ks++)
            load_a_frag(A, row, ok, kq, ks, scale, shift, BN, ah[mt][ks], al[mt][ks]);
    }

    f32x4 acc[2][8];
#pragma unroll
    for (int mt = 0; mt < 2; mt++)
#pragma unroll
        for (int nt = 0; nt < 8; nt++) acc[mt][nt] = (f32x4){0.f, 0.f, 0.f, 0.f};

#pragma unroll
    for (int nt = 0; nt < 8; nt++) {
        const unsigned short* pbh = Fh + ((size_t)nt * 4 * 64 + lane) * 8;
        const unsigned short* pbl = Fl + ((size_t)nt * 4 * 64 + lane) * 8;
        bf16x8 bh[4], bl[4];
#pragma unroll
        for (int ks = 0; ks < 4; ks++) {
            bh[ks] = *reinterpret_cast<const bf16x8*>(pbh + ks * 512);
            bl[ks] = *reinterpret_cast<const bf16x8*>(pbl + ks * 512);
        }
#pragma unroll
        for (int mt = 0; mt < 2; mt++)
#pragma unroll
            for (int ks = 0; ks < 4; ks++) {
                acc[mt][nt] = __builtin_amdgcn_mfma_f32_16x16x32_bf16(ah[mt][ks], bl[ks],
                                                                     acc[mt][nt], 0, 0, 0);
                acc[mt][nt] = __builtin_amdgcn_mfma_f32_16x16x32_bf16(al[mt][ks], bh[ks],
                                                                     acc[mt][nt], 0, 0, 0);
                acc[mt][nt] = __builtin_amdgcn_mfma_f32_16x16x32_bf16(ah[mt][ks], bh[ks],
                                                                     acc[mt][nt], 0, 0, 0);
            }
    }

#pragma unroll
    for (int mt = 0; mt < 2; mt++)
#pragma unroll
        for (int nt = 0; nt < 8; nt++)
#pragma unroll
            for (int r = 0; r < 4; r++) {
                size_t row = mrow0 + mt * 16 + kq * 4 + r;
                Cb[row * 128 + nt * 16 + r16] = f2bf(acc[mt][nt][r]);
            }
}

// ------ fused K=512 encoder GEMM (pre-BN'd bf16 A, split-bf16 W) + pool ----------
__global__ __launch_bounds__(256) void k_enc_pool(
    const unsigned short* __restrict__ Ub0, const unsigned short* __restrict__ Ub1,
    const unsigned short* __restrict__ Ub2, const unsigned short* __restrict__ Ub3,
    const unsigned short* __restrict__ Fh, const unsigned short* __restrict__ Fl,
    const float* __restrict__ encB, const int* __restrict__ batch,
    float* __restrict__ psum) {
    int lane = threadIdx.x & 63;
    int wid = threadIdx.x >> 6;
    int r16 = lane & 15, kq = lane >> 4;
    size_t brow0 = (size_t)blockIdx.x * 128;
    size_t mrow0 = brow0 + wid * 32;
    int colOff = blockIdx.y * 128;
    int ntBase = blockIdx.y * 8;

    __shared__ int batch_lds[128];
    if (threadIdx.x < 128) {
        size_t row = brow0 + threadIdx.x;
        batch_lds[threadIdx.x] = (row < N_NODES) ? batch[row] : -1;
    }
    __syncthreads();

    f32x4 acc[2][8];
#pragma unroll
    for (int mt = 0; mt < 2; mt++)
#pragma unroll
        for (int nt = 0; nt < 8; nt++) acc[mt][nt] = (f32x4){0.f, 0.f, 0.f, 0.f};

    const unsigned short* Ubs[4] = {Ub0, Ub1, Ub2, Ub3};
#pragma unroll 1
    for (int l = 0; l < 4; l++) {
        const unsigned short* Ub = Ubs[l];
        bf16x8 ah[2][4];
#pragma unroll
        for (int mt = 0; mt < 2; mt++) {
            size_t row = mrow0 + mt * 16 + r16;
            bool ok = row < N_NODES;
#pragma unroll
            for (int ks = 0; ks < 4; ks++) {
                if (ok)
                    ah[mt][ks] = *reinterpret_cast<const bf16x8*>(
                        Ub + row * 128 + ks * 32 + kq * 8);
                else
                    ah[mt][ks] = (bf16x8){0, 0, 0, 0, 0, 0, 0, 0};
            }
        }
        const unsigned short* Fhl = Fh + (size_t)l * 32768;
        const unsigned short* Fll = Fl + (size_t)l * 32768;
#pragma unroll
        for (int nt = 0; nt < 8; nt++) {
            const unsigned short* pbh = Fhl + ((size_t)(ntBase + nt) * 4 * 64 + lane) * 8;
            const unsigned short* pbl = Fll + ((size_t)(ntBase + nt) * 4 * 64 + lane) * 8;
            bf16x8 bh[4], bl[4];
#pragma unroll
            for (int ks = 0; ks < 4; ks++) {
                bh[ks] = *reinterpret_cast<const bf16x8*>(pbh + ks * 512);
                bl[ks] = *reinterpret_cast<const bf16x8*>(pbl + ks * 512);
            }
#pragma unroll
            for (int mt = 0; mt < 2; mt++)
#pragma unroll
                for (int ks = 0; ks < 4; ks++) {
                    acc[mt][nt] = __builtin_amdgcn_mfma_f32_16x16x32_bf16(
                        ah[mt][ks], bl[ks], acc[mt][nt], 0, 0, 0);
                    acc[mt][nt] = __builtin_amdgcn_mfma_f32_16x16x32_bf16(
                        ah[mt][ks], bh[ks], acc[mt][nt], 0, 0, 0);
                }
        }
    }

    // relu(acc + encB), pads zeroed
    float bias[8];
#pragma unroll
    for (int nt = 0; nt < 8; nt++) bias[nt] = encB[colOff + nt * 16 + r16];
#pragma unroll
    for (int mt = 0; mt < 2; mt++)
#pragma unroll
        for (int r = 0; r < 4; r++) {
            bool valid = batch_lds[wid * 32 + mt * 16 + kq * 4 + r] >= 0;
#pragma unroll
            for (int nt = 0; nt < 8; nt++)
                acc[mt][nt][r] = valid ? fmaxf(acc[mt][nt][r] + bias[nt], 0.f) : 0.f;
        }

    // segment pool (batch sorted; block spans few graphs)
    int lastIdx = (int)((N_NODES - 1 - brow0) < 127 ? (N_NODES - 1 - brow0) : 127);
    int g0 = batch_lds[0];
    int g1 = batch_lds[lastIdx];
    __shared__ float sred[4][128];
    for (int g = g0; g <= g1; ++g) {
        float s[8];
#pragma unroll
        for (int nt = 0; nt < 8; nt++) s[nt] = 0.f;
#pragma unroll
        for (int mt = 0; mt < 2; mt++)
#pragma unroll
            for (int r = 0; r < 4; r++) {
                bool m = batch_lds[wid * 32 + mt * 16 + kq * 4 + r] == g;
                if (m) {
#pragma unroll
                    for (int nt = 0; nt < 8; nt++) s[nt] += acc[mt][nt][r];
                }
            }
#pragma unroll
        for (int nt = 0; nt < 8; nt++) {
            s[nt] += __shfl_xor(s[nt], 16);
            s[nt] += __shfl_xor(s[nt], 32);
        }
        if (lane < 16) {
#pragma unroll
            for (int nt = 0; nt < 8; nt++) sred[wid][nt * 16 + r16] = s[nt];
        }
        __syncthreads();
        if (threadIdx.x < 128) {
            float tot = sred[0][threadIdx.x] + sred[1][threadIdx.x] +
                        sred[2][threadIdx.x] + sred[3][threadIdx.x];
            atomicAdd(&psum[(size_t)g * ENCDIM + colOff + threadIdx.x], tot);
        }
        __syncthreads();
    }
}

// ------ aggregation: gather bf16 hw; Uf(fp32) + Ub(raw bf16) <- S * hw + bias ----
__global__ __launch_bounds__(256) void k_agg(const unsigned short* __restrict__ hwb,
                                             const int* __restrict__ rs,
                                             const int* __restrict__ cnt,
                                             const int2* __restrict__ csr_ew,
                                             const float* __restrict__ dinv,
                                             const float4* __restrict__ bias4,
                                             float4* __restrict__ Uf4,
                                             unsigned short* __restrict__ Ub) {
    int n = blockIdx.x * 8 + (threadIdx.x >> 5);
    int lane = threadIdx.x & 31;
    if (n >= N_NODES) return;
    float d = dinv[n];
    float dd = d * d;
    ushort4 sb = *(const ushort4*)(hwb + (size_t)n * 128 + lane * 4);
    float4 b = bias4[lane];
    float4 acc;
    acc.x = fmaf(dd, bf2f(sb.x), b.x);
    acc.y = fmaf(dd, bf2f(sb.y), b.y);
    acc.z = fmaf(dd, bf2f(sb.z), b.z);
    acc.w = fmaf(dd, bf2f(sb.w), b.w);
    int s0 = rs[n];
    int c = cnt[n];
    int e = 0;
    for (; e + 8 <= c; e += 8) {
        int2 ee[8];
        ushort4 vv[8];
#pragma unroll
        for (int u = 0; u < 8; u++) ee[u] = csr_ew[s0 + e + u];
#pragma unroll
        for (int u = 0; u < 8; u++)
            vv[u] = *(const ushort4*)(hwb + (size_t)ee[u].x * 128 + lane * 4);
#pragma unroll
        for (int u = 0; u < 8; u++) {
            float w = __int_as_float(ee[u].y);
            acc.x = fmaf(w, bf2f(vv[u].x), acc.x);
            acc.y = fmaf(w, bf2f(vv[u].y), acc.y);
            acc.z = fmaf(w, bf2f(vv[u].z), acc.z);
            acc.w = fmaf(w, bf2f(vv[u].w), acc.w);
        }
    }
    for (; e < c; e++) {
        int2 ee = csr_ew[s0 + e];
        ushort4 v = *(const ushort4*)(hwb + (size_t)ee.x * 128 + lane * 4);
        float w = __int_as_float(ee.y);
        acc.x = fmaf(w, bf2f(v.x), acc.x);
        acc.y = fmaf(w, bf2f(v.y), acc.y);
        acc.z = fmaf(w, bf2f(v.z), acc.z);
        acc.w = fmaf(w, bf2f(v.w), acc.w);
    }
    Uf4[(size_t)n * 32 + lane] = acc;
    ushort4 bv;
    bv.x = f2bf(acc.x);
    bv.y = f2bf(acc.y);
    bv.z = f2bf(acc.z);
    bv.w = f2bf(acc.w);
    *(ushort4*)(Ub + (size_t)n * 128 + lane * 4) = bv;
}

// ---------------- BN stats on fp32 Uf ----------------
__global__ __launch_bounds__(256) void k_bn_stats(const float4* __restrict__ Uf4,
                                                  float* __restrict__ sum,
                                                  float* __restrict__ sq) {
    int c4 = threadIdx.x & 31;  // float4 column = features 4*c4..4*c4+3
    int y = threadIdx.x >> 5;   // 8 row-groups
    float4 s = make_float4(0.f, 0.f, 0.f, 0.f);
    float4 q = make_float4(0.f, 0.f, 0.f, 0.f);
    for (size_t n = (size_t)blockIdx.x * 8 + y; n < N_NODES; n += (size_t)gridDim.x * 8) {
        float4 v = Uf4[n * 32 + c4];
        s.x += v.x; s.y += v.y; s.z += v.z; s.w += v.w;
        q.x = fmaf(v.x, v.x, q.x); q.y = fmaf(v.y, v.y, q.y);
        q.z = fmaf(v.z, v.z, q.z); q.w = fmaf(v.w, v.w, q.w);
    }
    __shared__ float4 ls[256], lq[256];
    ls[threadIdx.x] = s;
    lq[threadIdx.x] = q;
    __syncthreads();
    if (y == 0) {
#pragma unroll
        for (int yy = 1; yy < 8; yy++) {
            float4 a = ls[yy * 32 + c4], b = lq[yy * 32 + c4];
            s.x += a.x; s.y += a.y; s.z += a.z; s.w += a.w;
            q.x += b.x; q.y += b.y; q.z += b.z; q.w += b.w;
        }
        atomicAdd(&sum[c4 * 4 + 0], s.x);
        atomicAdd(&sum[c4 * 4 + 1], s.y);
        atomicAdd(&sum[c4 * 4 + 2], s.z);
        atomicAdd(&sum[c4 * 4 + 3], s.w);
        atomicAdd(&sq[c4 * 4 + 0], q.x);
        atomicAdd(&sq[c4 * 4 + 1], q.y);
        atomicAdd(&sq[c4 * 4 + 2], q.z);
        atomicAdd(&sq[c4 * 4 + 3], q.w);
    }
}

__global__ void k_bn_finalize(const float* __restrict__ sum, const float* __restrict__ sq,
                              const float* __restrict__ gamma, const float* __restrict__ beta,
                              float* __restrict__ scale, float* __restrict__ shift) {
    int f = threadIdx.x;
    float mu = sum[f] * (1.0f / N_NODES);
    float var = sq[f] * (1.0f / N_NODES) - mu * mu;
    float s = rsqrtf(var + EPS_BN) * gamma[f];
    scale[f] = s;
    shift[f] = beta[f] - mu * s;
}

// ------ in-place BN+ReLU on bf16 activation buffer (pre-pass for encoder) -------
__global__ __launch_bounds__(256) void k_bnapply(uint4* __restrict__ Ub4,
                                                 const float* __restrict__ scale,
                                                 const float* __restrict__ shift) {
    size_t i = (size_t)blockIdx.x * 256 + threadIdx.x;  // NPAD*16 uint4s
    int f0 = (int)(i & 15) * 8;
    float4 sc0 = *(const float4*)&scale[f0];
    float4 sc1 = *(const float4*)&scale[f0 + 4];
    float4 sh0 = *(const float4*)&shift[f0];
    float4 sh1 = *(const float4*)&shift[f0 + 4];
    uint4 v = Ub4[i];
    float a0 = fmaxf(fmaf(bf2f(v.x & 0xffffu), sc0.x, sh0.x), 0.f);
    float a1 = fmaxf(fmaf(bf2f(v.x >> 16), sc0.y, sh0.y), 0.f);
    float a2 = fmaxf(fmaf(bf2f(v.y & 0xffffu), sc0.z, sh0.z), 0.f);
    float a3 = fmaxf(fmaf(bf2f(v.y >> 16), sc0.w, sh0.w), 0.f);
    float a4 = fmaxf(fmaf(bf2f(v.z & 0xffffu), sc1.x, sh1.x), 0.f);
    float a5 = fmaxf(fmaf(bf2f(v.z >> 16), sc1.y, sh1.y), 0.f);
    float a6 = fmaxf(fmaf(bf2f(v.w & 0xffffu), sc1.z, sh1.z), 0.f);
    float a7 = fmaxf(fmaf(bf2f(v.w >> 16), sc1.w, sh1.w), 0.f);
    uint4 o;
    o.x = (unsigned int)f2bf(a0) | ((unsigned int)f2bf(a1) << 16);
    o.y = (unsigned int)f2bf(a2) | ((unsigned int)f2bf(a3) << 16);
    o.z = (unsigned int)f2bf(a4) | ((unsigned int)f2bf(a5) << 16);
    o.w = (unsigned int)f2bf(a6) | ((unsigned int)f2bf(a7) << 16);
    Ub4[i] = o;
}

// ---------------- decoder (mean-divide folded in) ----------------
__global__ __launch_bounds__(128) void k_dec(const float* __restrict__ psum,
                                             const int* __restrict__ gcnt,
                                             const float* __restrict__ W1,
                                             const float* __restrict__ b1,
                                             const float* __restrict__ W2,
                                             const float* __restrict__ b2,
                                             float* __restrict__ out) {
    int g = blockIdx.x;
    int j = threadIdx.x;
    float inv = 1.0f / fmaxf((float)gcnt[g], 1.0f);
    const float* p = &psum[g * ENCDIM];
    float acc = b1[j];
    for (int k = 0; k < ENCDIM; k++) acc = fmaf(p[k] * inv, W1[k * 128 + j], acc);
    float h = fmaxf(acc, 0.f) * W2[j];
    for (int off = 32; off; off >>= 1) h += __shfl_down(h, off);
    __shared__ float red[2];
    if ((j & 63) == 0) red[j >> 6] = h;
    __syncthreads();
    if (j == 0) out[g] = red[0] + red[1] + b2[0];
}

extern "C" void kernel_launch(void* const* d_in, const int* in_sizes, int n_in,
                              void* d_out, int out_size, void* d_ws, size_t ws_size,
                              hipStream_t stream) {
    const float* x = (const float*)d_in[0];
    const int* ei = (const int*)d_in[1];
    const int* src = ei;
    const int* dst = ei + N_EDGES;
    const int* batch = (const int*)d_in[2];
    const float* convW = (const float*)d_in[3];
    const float* convB = (const float*)d_in[4];
    const float* gamma = (const float*)d_in[5];
    const float* beta = (const float*)d_in[6];
    const float* encW = (const float*)d_in[7];
    const float* encB = (const float*)d_in[8];
    const float* dW1 = (const float*)d_in[9];
    const float* db1 = (const float*)d_in[10];
    const float* dW2 = (const float*)d_in[11];
    const float* db2 = (const float*)d_in[12];
    float* out = (float*)d_out;

    char* w = (char*)d_ws;
    auto alloc = [&](size_t bytes) {
        char* p = w;
        w += (bytes + 255) & ~(size_t)255;
        return p;
    };
    // workspace budget ~196 MB (within proven 221 MB envelope)
    int* cnt = (int*)alloc((size_t)N_NODES * 4);
    int* rs = (int*)alloc((size_t)N_NODES * 4);
    int* cursor = (int*)alloc((size_t)N_NODES * 4);
    int* bsums = (int*)alloc(512 * 4);
    float* dinv = (float*)alloc((size_t)N_NODES * 4);
    int2* csr_ew = (int2*)alloc((size_t)N_EDGES * 8);
    float* Uf = (float*)alloc((size_t)N_NODES * HDIM * 4);         // raw agg out (fp32)
    unsigned short* B = (unsigned short*)alloc((size_t)NPAD * HDIM * 2);  // hw bf16
    unsigned short* Ubf[NLAYERS];                                  // raw agg out (bf16)
    for (int l = 0; l < NLAYERS; l++)
        Ubf[l] = (unsigned short*)alloc((size_t)NPAD * HDIM * 2);
    unsigned short* convWfh = (unsigned short*)alloc((size_t)NLAYERS * 16384 * 2);
    unsigned short* convWfl = (unsigned short*)alloc((size_t)NLAYERS * 16384 * 2);
    unsigned short* encWfh = (unsigned short*)alloc((size_t)NLAYERS * 32768 * 2);
    unsigned short* encWfl = (unsigned short*)alloc((size_t)NLAYERS * 32768 * 2);
    float* bnsumAll = (float*)alloc(NLAYERS * 128 * 4);
    float* bnsqAll = (float*)alloc(NLAYERS * 128 * 4);
    float* bnscaleAll = (float*)alloc(NLAYERS * 128 * 4);
    float* bnshiftAll = (float*)alloc(NLAYERS * 128 * 4);
    int* gcnt = (int*)alloc(256 * 4);
    int* gstart = (int*)alloc(256 * 4);
    float* psum = (float*)alloc(256 * 256 * 4);

    // zero init (one batch)
    hipMemsetAsync(cnt, 0, (size_t)N_NODES * 4, stream);
    hipMemsetAsync(bnsumAll, 0, NLAYERS * 128 * 4, stream);
    hipMemsetAsync(bnsqAll, 0, NLAYERS * 128 * 4, stream);
    hipMemsetAsync(psum, 0, 256 * 256 * 4, stream);

    // CSR build + degree normalization
    k_count<<<(N_EDGES + 255) / 256, 256, 0, stream>>>(dst, cnt);
    k_dinv<<<(N_NODES + 255) / 256, 256, 0, stream>>>(cnt, dinv);
    int nb = (N_NODES + 255) / 256;  // 391
    k_scan_block<<<nb, 256, 0, stream>>>(cnt, rs, bsums);
    k_scan_sums<<<1, 512, 0, stream>>>(bsums, nb);
    k_scan_add<<<nb, 256, 0, stream>>>(rs, bsums, cursor);
    k_scatter<<<(N_EDGES + 255) / 256, 256, 0, stream>>>(src, dst, dinv, cursor, csr_ew);
    k_gbounds<<<1, 256, 0, stream>>>(batch, gstart, gcnt);

    // weight fragment permute + split (tiny)
    for (int l = 0; l < NLAYERS; l++) {
        k_wfrag<<<8, 256, 0, stream>>>(convW + (size_t)l * 16384, 128, 8,
                                       convWfh + (size_t)l * 16384,
                                       convWfl + (size_t)l * 16384);
        k_wfrag<<<16, 256, 0, stream>>>(encW + (size_t)l * 128 * 256, 256, 16,
                                        encWfh + (size_t)l * 32768,
                                        encWfl + (size_t)l * 32768);
    }

    for (int l = 0; l < NLAYERS; l++) {
        // hw(bf16) = h @ convW_l  (h = x for l=0, else BN_{l-1}(Uf) fused)
        if (l == 0)
            k_mfma<0><<<NPAD / 128, 256, 0, stream>>>(
                x, convWfh + (size_t)l * 16384, convWfl + (size_t)l * 16384,
                nullptr, nullptr, B);
        else
            k_mfma<1><<<NPAD / 128, 256, 0, stream>>>(
                Uf, convWfh + (size_t)l * 16384, convWfl + (size_t)l * 16384,
                bnscaleAll + (l - 1) * 128, bnshiftAll + (l - 1) * 128, B);
        // aggregate (bf16 gather) + bias -> Uf (fp32) + Ubf[l] (raw bf16)
        k_agg<<<N_NODES / 8, 256, 0, stream>>>(B, rs, cnt, csr_ew, dinv,
                                               (const float4*)(convB + l * 128),
                                               (float4*)Uf, Ubf[l]);
        // BN stats + scale/shift
        k_bn_stats<<<512, 256, 0, stream>>>((const float4*)Uf, bnsumAll + l * 128,
                                            bnsqAll + l * 128);
        k_bn_finalize<<<1, 128, 0, stream>>>(bnsumAll + l * 128, bnsqAll + l * 128,
                                             gamma + l * 128, beta + l * 128,
                                             bnscaleAll + l * 128, bnshiftAll + l * 128);
        // pre-apply BN+ReLU to the encoder's bf16 copy (in place)
        k_bnapply<<<NPAD * 16 / 256, 256, 0, stream>>>((uint4*)Ubf[l],
                                                       bnscaleAll + l * 128,
                                                       bnshiftAll + l * 128);
    }

    // fused K=512 encoder GEMM + bias + ReLU + segment pool
    k_enc_pool<<<dim3(NPAD / 128, 2), 256, 0, stream>>>(
        Ubf[0], Ubf[1], Ubf[2], Ubf[3], encWfh, encWfl, encB, batch, psum);
    k_dec<<<256, 128, 0, stream>>>(psum, gcnt, dW1, db1, dW2, db2, out);
}